// Round 1
// baseline (10407.785 us; speedup 1.0000x reference)
//
#include <hip/hip_runtime.h>
#include <stdint.h>

#define BB 256
#define NN 2048
#define NCORE 8
#define TSIM 32
#define PLANE (BB*NN)   // 524288

// ---------------- zero init (memb + counts) ----------------
__global__ void zero_f32_kernel(float* __restrict__ p, int n4) {
  int i = blockIdx.x * 256 + threadIdx.x;
  if (i < n4) ((float4*)p)[i] = make_float4(0.f, 0.f, 0.f, 0.f);
}

// ---------------- spike-train precompute (bit-exact port of to_uniform_spikes) ----------------
__global__ void spikes_kernel(const float* __restrict__ x, uint8_t* __restrict__ strain) {
  int idx = blockIdx.x * 256 + threadIdx.x;   // over PLANE/4
  float4 xv = ((const float4*)x)[idx];
  float xs0 = xv.x, xs1 = xv.y, xs2 = xv.z, xs3 = xv.w;
  float nsf[4], sp[4];
  int   ns[4];
  nsf[0] = rintf(xs0 * 32.0f); nsf[1] = rintf(xs1 * 32.0f);
  nsf[2] = rintf(xs2 * 32.0f); nsf[3] = rintf(xs3 * 32.0f);
#pragma unroll
  for (int e = 0; e < 4; ++e) {
    ns[e] = (int)nsf[e];
    sp[e] = 32.0f / fmaxf(nsf[e], 1.0f);   // spacing = T / N_safe
  }
  for (int t = 0; t < TSIM; ++t) {
    float ct = (float)t;
    uint8_t bt[4];
#pragma unroll
    for (int e = 0; e < 4; ++e) {
      bool res;
      if (ns[e] == TSIM)      res = true;    // where(Ns==T, 1, ...)
      else if (ns[e] == 0)    res = false;   // mask false
      else {
        float q = floorf(ct / sp[e]);
        float m = fmodf(ct, sp[e]);          // positive args: == jnp.mod
        res = (q < nsf[e]) && (floorf(m) == 0.0f);
      }
      bt[e] = res ? (uint8_t)1 : (uint8_t)0;
    }
    ((uchar4*)(strain + (size_t)t * PLANE))[idx] = make_uchar4(bt[0], bt[1], bt[2], bt[3]);
  }
}

// ---------------- one pipeline step: delta = S @ W[c], membrane update ----------------
// grid: (32 o-tiles, n_active_cores), block: 512 threads
// thread (to = tid&15 -> 4 o's, tb = tid>>4 -> 8 b's), acc[8][4]
__global__ __launch_bounds__(512) void step_kernel(
    const float* __restrict__ W, const float* __restrict__ thresholds,
    const uint8_t* __restrict__ strain,
    const uint8_t* __restrict__ buf_prev, uint8_t* __restrict__ buf_cur,
    float* __restrict__ memb, float* __restrict__ counts, float* __restrict__ out,
    int t, int c_lo) {
  __shared__ float sB[32][64];
  const int c  = c_lo + blockIdx.y;
  const int tid = threadIdx.x;
  const int to = tid & 15;
  const int tb = tid >> 4;             // 0..31
  const int o0 = blockIdx.x * 64;
  const float thr = thresholds[c];
  const uint8_t* Asrc = (c == 0) ? (strain + (size_t)t * PLANE)
                                 : (buf_prev + (size_t)(c - 1) * PLANE);
  const float* Wc = W + (size_t)c * NN * NN;

  float acc[8][4];
#pragma unroll
  for (int i = 0; i < 8; ++i)
#pragma unroll
    for (int j = 0; j < 4; ++j) acc[i][j] = 0.f;

  for (int k0 = 0; k0 < NN; k0 += 32) {
    {
      int row = tid >> 4;              // 0..31
      int col = (tid & 15) << 2;       // 0..60
      float4 wv = *(const float4*)(Wc + (size_t)(k0 + row) * NN + (o0 + col));
      *(float4*)&sB[row][col] = wv;
    }
    __syncthreads();
#pragma unroll
    for (int kk = 0; kk < 32; kk += 4) {
      float a[8][4];
#pragma unroll
      for (int bb = 0; bb < 8; ++bb) {
        uchar4 av = *(const uchar4*)(Asrc + (size_t)(tb * 8 + bb) * NN + (k0 + kk));
        a[bb][0] = (float)av.x; a[bb][1] = (float)av.y;
        a[bb][2] = (float)av.z; a[bb][3] = (float)av.w;
      }
#pragma unroll
      for (int j = 0; j < 4; ++j) {
        float4 w = *(const float4*)&sB[kk + j][to << 2];
#pragma unroll
        for (int bb = 0; bb < 8; ++bb) {
          acc[bb][0] = fmaf(a[bb][j], w.x, acc[bb][0]);
          acc[bb][1] = fmaf(a[bb][j], w.y, acc[bb][1]);
          acc[bb][2] = fmaf(a[bb][j], w.z, acc[bb][2]);
          acc[bb][3] = fmaf(a[bb][j], w.w, acc[bb][3]);
        }
      }
    }
    __syncthreads();
  }

  // epilogue: memb += delta; fired = thr < memb; memb -= thr where fired; buf = fired
  float*   membc = memb + (size_t)c * PLANE;
  uint8_t* bufc  = buf_cur + (size_t)c * PLANE;
#pragma unroll
  for (int bb = 0; bb < 8; ++bb) {
    int b = tb * 8 + bb;
    size_t idx = (size_t)b * NN + o0 + (to << 2);
    float4 m = *(float4*)(membc + idx);
    m.x += acc[bb][0]; m.y += acc[bb][1]; m.z += acc[bb][2]; m.w += acc[bb][3];
    uchar4 f;
    f.x = (thr < m.x) ? 1 : 0; f.y = (thr < m.y) ? 1 : 0;
    f.z = (thr < m.z) ? 1 : 0; f.w = (thr < m.w) ? 1 : 0;
    if (f.x) m.x -= thr;  if (f.y) m.y -= thr;
    if (f.z) m.z -= thr;  if (f.w) m.w -= thr;
    *(float4*)(membc + idx) = m;
    *(uchar4*)(bufc + idx) = f;
    if (c == NCORE - 1) {
      float4 cv = *(float4*)(counts + idx);
      cv.x += (float)f.x; cv.y += (float)f.y; cv.z += (float)f.z; cv.w += (float)f.w;
      if (t == TSIM + NCORE - 2) {   // t == 38, last step: write output = counts / 32
        *(float4*)(out + idx) = make_float4(cv.x * 0.03125f, cv.y * 0.03125f,
                                            cv.z * 0.03125f, cv.w * 0.03125f);
      } else {
        *(float4*)(counts + idx) = cv;
      }
    }
  }
}

extern "C" void kernel_launch(void* const* d_in, const int* in_sizes, int n_in,
                              void* d_out, int out_size, void* d_ws, size_t ws_size,
                              hipStream_t stream) {
  const float* x   = (const float*)d_in[0];
  const float* W   = (const float*)d_in[1];
  const float* thr = (const float*)d_in[2];
  float* out = (float*)d_out;

  // workspace layout (≈44 MB):
  //   memb   : 8*PLANE f32   (16.78 MB)
  //   counts : 1*PLANE f32   ( 2.10 MB)
  //   strain : 32*PLANE u8   (16.78 MB)
  //   buf0   : 8*PLANE u8    ( 4.19 MB)
  //   buf1   : 8*PLANE u8    ( 4.19 MB)
  uint8_t* ws = (uint8_t*)d_ws;
  float*   memb   = (float*)ws;
  float*   counts = (float*)(ws + (size_t)8 * PLANE * 4);
  uint8_t* strain = ws + (size_t)9 * PLANE * 4;
  uint8_t* buf0   = strain + (size_t)32 * PLANE;
  uint8_t* buf1   = buf0 + (size_t)8 * PLANE;

  // zero memb + counts (contiguous 9*PLANE floats)
  int n4 = 9 * PLANE / 4;                    // 1,179,648 float4
  zero_f32_kernel<<<dim3(n4 / 256), 256, 0, stream>>>(memb, n4);
  // precompute spike trains
  spikes_kernel<<<dim3(PLANE / 4 / 256), 256, 0, stream>>>(x, strain);

  for (int t = 0; t < TSIM + NCORE - 1; ++t) {     // 39 steps
    int c_lo = (t > TSIM - 1) ? (t - (TSIM - 1)) : 0;
    int c_hi = (t < NCORE - 1) ? t : (NCORE - 1);
    // core c at step t reads buf written at step t-1 -> plane buf[(t-1)&1] == buf[(t+1)&1]
    uint8_t* prev = (t & 1) ? buf0 : buf1;
    uint8_t* cur  = (t & 1) ? buf1 : buf0;
    step_kernel<<<dim3(32, c_hi - c_lo + 1), 512, 0, stream>>>(
        W, thr, strain, prev, cur, memb, counts, out, t, c_lo);
  }
}

// Round 2
// 2648.559 us; speedup vs baseline: 3.9296x; 3.9296x over previous
//
#include <hip/hip_runtime.h>
#include <stdint.h>

#define BB 256
#define NN 2048
#define NCORE 8
#define TSIM 32
#define NSTEP 39
#define PLANE_E (BB*NN)        // 524288 elements
#define PLANE_B (PLANE_E*2)    // 1 MiB bf16 plane
#define ROWB (NN*2)            // 4096 B per row

typedef short s8v __attribute__((ext_vector_type(8)));
typedef float f4v __attribute__((ext_vector_type(4)));

__device__ __forceinline__ void load_lds16(const void* g, void* l) {
  __builtin_amdgcn_global_load_lds((const __attribute__((address_space(1))) void*)g,
                                   (__attribute__((address_space(3))) void*)l, 16, 0, 0);
}

// ---------------- zero init ----------------
__global__ void zero_f32_kernel(float* __restrict__ p, int n4) {
  int i = blockIdx.x * 256 + threadIdx.x;
  if (i < n4) ((float4*)p)[i] = make_float4(0.f, 0.f, 0.f, 0.f);
}

// =====================================================================
// PRIMARY PATH (needs 256 MiB ws): MFMA with exact 3-term bf16 split
// =====================================================================

// Swizzled bf16 spike trains: plane[t], byte(b,k) = b*4096 + (k>>5)*64 +
//   ((((k>>3)&3) ^ ((b>>1)&3))<<4) + (k&7)*2
__global__ void spikes_bf16_kernel(const float* __restrict__ x, uint8_t* __restrict__ strain) {
  int t = blockIdx.x * 256 + threadIdx.x;    // over BB*NN/8
  int b = t >> 8;
  int oct = t & 255;                         // k-octet index (k0 = oct*8)
  const float* xp = x + (size_t)b * NN + oct * 8;
  float nsf[8], sp[8]; int ns[8];
#pragma unroll
  for (int e = 0; e < 8; ++e) {
    float nv = rintf(xp[e] * 32.0f);
    nsf[e] = nv; ns[e] = (int)nv; sp[e] = 32.0f / fmaxf(nv, 1.0f);
  }
  uint32_t base = (uint32_t)b * ROWB + ((uint32_t)(oct >> 2) << 6)
                + ((uint32_t)((oct & 3) ^ ((b >> 1) & 3)) << 4);
  for (int cyc = 0; cyc < TSIM; ++cyc) {
    float ct = (float)cyc;
    uint16_t v[8];
#pragma unroll
    for (int e = 0; e < 8; ++e) {
      bool res;
      if (ns[e] == TSIM)      res = true;
      else if (ns[e] == 0)    res = false;
      else {
        float q = floorf(ct / sp[e]);
        float m = fmodf(ct, sp[e]);
        res = (q < nsf[e]) && (floorf(m) == 0.0f);
      }
      v[e] = res ? (uint16_t)0x3F80 : (uint16_t)0;
    }
    uint4 pk;
    pk.x = (uint32_t)v[0] | ((uint32_t)v[1] << 16);
    pk.y = (uint32_t)v[2] | ((uint32_t)v[3] << 16);
    pk.z = (uint32_t)v[4] | ((uint32_t)v[5] << 16);
    pk.w = (uint32_t)v[6] | ((uint32_t)v[7] << 16);
    *(uint4*)(strain + (size_t)cyc * PLANE_B + base) = pk;
  }
}

// Split W (fp32 [c][k][n]) into 3 bf16 planes, tiled+swizzled:
// plane layout: [(c*32+nt)*64 + ks] chunks of 4096 B; chunk: n'(64) rows of 64 B,
// phys slot = (r>>3) ^ ((n'>>1)&3), holding k = ks*32 + slot*8 + e, n = nt*64 + n'.
__global__ __launch_bounds__(256) void wsplit_kernel(const float* __restrict__ W,
    uint8_t* __restrict__ Wh, uint8_t* __restrict__ Wm, uint8_t* __restrict__ Wl) {
  __shared__ uint8_t lds[3 * 4096];
  int ks = blockIdx.x, nt = blockIdx.y, c = blockIdx.z;
  int tid = threadIdx.x;
  const float* Wbase = W + ((size_t)c * NN + (size_t)ks * 32) * NN + nt * 64;
#pragma unroll
  for (int half = 0; half < 2; ++half) {
    int fi = tid * 2 + half;
    int r = fi >> 4, c16 = fi & 15;
    float4 wv = *(const float4*)(Wbase + (size_t)r * NN + c16 * 4);
    float w[4] = {wv.x, wv.y, wv.z, wv.w};
#pragma unroll
    for (int j = 0; j < 4; ++j) {
      int np = c16 * 4 + j;
      uint32_t u = __float_as_uint(w[j]);
      uint16_t h = (uint16_t)(u >> 16);                       // truncate (exact split)
      float r1 = w[j] - __uint_as_float(u & 0xFFFF0000u);     // exact (Sterbenz)
      uint32_t u1 = __float_as_uint(r1);
      uint16_t mm = (uint16_t)(u1 >> 16);
      float r2 = r1 - __uint_as_float(u1 & 0xFFFF0000u);      // exact
      uint32_t u2 = __float_as_uint(r2);
      uint16_t ll = (uint16_t)((u2 + 0x7FFFu + ((u2 >> 16) & 1u)) >> 16);  // RTNE
      uint32_t off = (uint32_t)np * 64
                   + ((uint32_t)(((r >> 3) ^ ((np >> 1) & 3))) << 4) + ((r & 7) << 1);
      *(uint16_t*)(lds + off)        = h;
      *(uint16_t*)(lds + 4096 + off) = mm;
      *(uint16_t*)(lds + 8192 + off) = ll;
    }
  }
  __syncthreads();
  size_t chunk = (((size_t)c * 32 + nt) * 64 + ks) * 4096 + (size_t)tid * 16;
  *(uint4*)(Wh + chunk) = *(const uint4*)(lds + tid * 16);
  *(uint4*)(Wm + chunk) = *(const uint4*)(lds + 4096 + tid * 16);
  *(uint4*)(Wl + chunk) = *(const uint4*)(lds + 8192 + tid * 16);
}

// One pipeline step: delta = S @ W[c] via MFMA, membrane update.
// grid (32 n-tiles, active cores), 256 threads (4 waves: wm=wid>>1, wn=wid&1).
__global__ __launch_bounds__(256) void step_mfma_kernel(
    const uint8_t* __restrict__ Wh, const uint8_t* __restrict__ Wm, const uint8_t* __restrict__ Wl,
    const float* __restrict__ thresholds, const uint8_t* __restrict__ strain,
    const uint8_t* __restrict__ buf_prev, uint8_t* __restrict__ buf_cur,
    float* __restrict__ memb, float* __restrict__ out, int t, int c_lo) {
  __shared__ uint8_t smem[57344];   // A: 2x16384 | B: 2x12288 ; epilogue overlay [128][72] f32
  const int tid = threadIdx.x;
  const int nt = blockIdx.x;
  const int c = c_lo + blockIdx.y;
  const int l = tid & 63, wid = tid >> 6;
  const int wm = wid >> 1, wn = wid & 1;
  const int lr = l & 15, lh = l >> 4;

  const uint8_t* Asrc = (c == 0) ? (strain + (size_t)t * PLANE_B)
                                 : (buf_prev + (size_t)(c - 1) * PLANE_B);
  size_t wchunk = (((size_t)c * 32 + nt) * 64) * 4096 + (size_t)tid * 16;
  const uint8_t* wsrc0 = Wh + wchunk;
  const uint8_t* wsrc1 = Wm + wchunk;
  const uint8_t* wsrc2 = Wl + wchunk;

  // per-thread A DMA sources (4 insts cover 256 rows x 64 B)
  const uint8_t* asrc0; const uint8_t* asrc1; const uint8_t* asrc2; const uint8_t* asrc3;
  {
    int i0 = 0 * 256 + tid, i1 = 1 * 256 + tid, i2 = 2 * 256 + tid, i3 = 3 * 256 + tid;
    asrc0 = Asrc + (size_t)(i0 >> 2) * ROWB + (i0 & 3) * 16;
    asrc1 = Asrc + (size_t)(i1 >> 2) * ROWB + (i1 & 3) * 16;
    asrc2 = Asrc + (size_t)(i2 >> 2) * ROWB + (i2 & 3) * 16;
    asrc3 = Asrc + (size_t)(i3 >> 2) * ROWB + (i3 & 3) * 16;
  }
  // fragment LDS offsets (mi/nj add 1024; swizzle phase invariant under +16 rows)
  const int R0 = wm * 128 + lr;
  const uint32_t aoff = (uint32_t)R0 * 64 + ((uint32_t)(lh ^ ((R0 >> 1) & 3)) << 4);
  const int N0 = wn * 32 + lr;
  const uint32_t boff = (uint32_t)N0 * 64 + ((uint32_t)(lh ^ ((N0 >> 1) & 3)) << 4);

  f4v acc[8][2];
  const f4v fzero = {0.f, 0.f, 0.f, 0.f};
#pragma unroll
  for (int mi = 0; mi < 8; ++mi) { acc[mi][0] = fzero; acc[mi][1] = fzero; }

#define ISSUE(nch) do { \
    uint8_t* Ad_ = smem + ((nch) & 1) * 16384; \
    uint8_t* Bd_ = smem + 32768 + ((nch) & 1) * 12288; \
    load_lds16(asrc0 + (nch) * 64, Ad_ + (0 * 256 + tid) * 16); \
    load_lds16(asrc1 + (nch) * 64, Ad_ + (1 * 256 + tid) * 16); \
    load_lds16(asrc2 + (nch) * 64, Ad_ + (2 * 256 + tid) * 16); \
    load_lds16(asrc3 + (nch) * 64, Ad_ + (3 * 256 + tid) * 16); \
    load_lds16(wsrc0 + (size_t)(nch) * 4096, Bd_ + 0 * 4096 + tid * 16); \
    load_lds16(wsrc1 + (size_t)(nch) * 4096, Bd_ + 1 * 4096 + tid * 16); \
    load_lds16(wsrc2 + (size_t)(nch) * 4096, Bd_ + 2 * 4096 + tid * 16); \
  } while (0)

  ISSUE(0);
  for (int ks = 0; ks < 64; ++ks) {
    __syncthreads();                 // drains DMA for current buffer (vmcnt 0)
    if (ks < 63) ISSUE(ks + 1);      // prefetch next chunk into other buffer
    const uint8_t* Ab = smem + (ks & 1) * 16384;
    const uint8_t* Bb = smem + 32768 + (ks & 1) * 12288;
    s8v bf00 = *(const s8v*)(Bb + boff);
    s8v bf01 = *(const s8v*)(Bb + boff + 4096);
    s8v bf02 = *(const s8v*)(Bb + boff + 8192);
    s8v bf10 = *(const s8v*)(Bb + boff + 1024);
    s8v bf11 = *(const s8v*)(Bb + boff + 1024 + 4096);
    s8v bf12 = *(const s8v*)(Bb + boff + 1024 + 8192);
#pragma unroll
    for (int mi = 0; mi < 8; mi += 2) {
      s8v af0 = *(const s8v*)(Ab + aoff + mi * 1024);
      s8v af1 = *(const s8v*)(Ab + aoff + mi * 1024 + 1024);
      acc[mi][0]   = __builtin_amdgcn_mfma_f32_16x16x32_bf16(af0, bf00, acc[mi][0],   0, 0, 0);
      acc[mi+1][0] = __builtin_amdgcn_mfma_f32_16x16x32_bf16(af1, bf00, acc[mi+1][0], 0, 0, 0);
      acc[mi][1]   = __builtin_amdgcn_mfma_f32_16x16x32_bf16(af0, bf10, acc[mi][1],   0, 0, 0);
      acc[mi+1][1] = __builtin_amdgcn_mfma_f32_16x16x32_bf16(af1, bf10, acc[mi+1][1], 0, 0, 0);
      acc[mi][0]   = __builtin_amdgcn_mfma_f32_16x16x32_bf16(af0, bf01, acc[mi][0],   0, 0, 0);
      acc[mi+1][0] = __builtin_amdgcn_mfma_f32_16x16x32_bf16(af1, bf01, acc[mi+1][0], 0, 0, 0);
      acc[mi][1]   = __builtin_amdgcn_mfma_f32_16x16x32_bf16(af0, bf11, acc[mi][1],   0, 0, 0);
      acc[mi+1][1] = __builtin_amdgcn_mfma_f32_16x16x32_bf16(af1, bf11, acc[mi+1][1], 0, 0, 0);
      acc[mi][0]   = __builtin_amdgcn_mfma_f32_16x16x32_bf16(af0, bf02, acc[mi][0],   0, 0, 0);
      acc[mi+1][0] = __builtin_amdgcn_mfma_f32_16x16x32_bf16(af1, bf02, acc[mi+1][0], 0, 0, 0);
      acc[mi][1]   = __builtin_amdgcn_mfma_f32_16x16x32_bf16(af0, bf12, acc[mi][1],   0, 0, 0);
      acc[mi+1][1] = __builtin_amdgcn_mfma_f32_16x16x32_bf16(af1, bf12, acc[mi+1][1], 0, 0, 0);
    }
  }
#undef ISSUE

  // ---- epilogue: LDS transpose (two halves), then coalesced membrane update ----
  const float thr = thresholds[c];
  float* Cl = (float*)smem;                 // [128][72] f32
  const int o0 = nt * 64;
  float* membp = memb + (size_t)c * PLANE_E;
  uint8_t* bufc = buf_cur + (size_t)c * PLANE_B;
  const bool last = (t == NSTEP - 1);
#pragma unroll
  for (int half = 0; half < 2; ++half) {
    __syncthreads();
    if (wm == half) {
#pragma unroll
      for (int mi = 0; mi < 8; ++mi)
#pragma unroll
        for (int nj = 0; nj < 2; ++nj)
#pragma unroll
          for (int rg = 0; rg < 4; ++rg)
            Cl[(mi * 16 + lh * 4 + rg) * 72 + wn * 32 + nj * 16 + lr] = acc[mi][nj][rg];
    }
    __syncthreads();
#pragma unroll
    for (int p = 0; p < 8; ++p) {
      int rr = p * 16 + (tid >> 4);
      int b = half * 128 + rr;
      int c4 = (tid & 15) * 4;
      int o = o0 + c4;
      float4 d = *(const float4*)&Cl[rr * 72 + c4];
      size_t idx = (size_t)b * NN + o;
      float4 mv = *(float4*)(membp + idx);
      mv.x += d.x; mv.y += d.y; mv.z += d.z; mv.w += d.w;
      bool g0 = thr < mv.x, g1 = thr < mv.y, g2 = thr < mv.z, g3 = thr < mv.w;
      if (g0) mv.x -= thr;  if (g1) mv.y -= thr;
      if (g2) mv.z -= thr;  if (g3) mv.w -= thr;
      *(float4*)(membp + idx) = mv;
      uint32_t ba = (uint32_t)b * ROWB + ((uint32_t)(o >> 5) << 6)
                  + ((uint32_t)(((o >> 3) & 3) ^ ((b >> 1) & 3)) << 4) + ((o & 7) << 1);
      uint2 pk;
      pk.x = (g0 ? 0x3F80u : 0u) | ((g1 ? 0x3F80u : 0u) << 16);
      pk.y = (g2 ? 0x3F80u : 0u) | ((g3 ? 0x3F80u : 0u) << 16);
      *(uint2*)(bufc + ba) = pk;
      if (c == NCORE - 1) {
        float4 cv = *(float4*)(out + idx);
        cv.x += g0 ? 1.f : 0.f; cv.y += g1 ? 1.f : 0.f;
        cv.z += g2 ? 1.f : 0.f; cv.w += g3 ? 1.f : 0.f;
        if (last) { cv.x *= 0.03125f; cv.y *= 0.03125f; cv.z *= 0.03125f; cv.w *= 0.03125f; }
        *(float4*)(out + idx) = cv;
      }
    }
  }
}

// =====================================================================
// FALLBACK PATH (round-1, fp32 VALU) — used when ws_size < 256 MiB
// =====================================================================
__global__ void spikes_kernel(const float* __restrict__ x, uint8_t* __restrict__ strain) {
  int idx = blockIdx.x * 256 + threadIdx.x;
  float4 xv = ((const float4*)x)[idx];
  float xs[4] = {xv.x, xv.y, xv.z, xv.w};
  float nsf[4], sp[4]; int ns[4];
#pragma unroll
  for (int e = 0; e < 4; ++e) {
    nsf[e] = rintf(xs[e] * 32.0f);
    ns[e] = (int)nsf[e];
    sp[e] = 32.0f / fmaxf(nsf[e], 1.0f);
  }
  for (int t = 0; t < TSIM; ++t) {
    float ct = (float)t;
    uint8_t bt[4];
#pragma unroll
    for (int e = 0; e < 4; ++e) {
      bool res;
      if (ns[e] == TSIM)      res = true;
      else if (ns[e] == 0)    res = false;
      else {
        float q = floorf(ct / sp[e]);
        float m = fmodf(ct, sp[e]);
        res = (q < nsf[e]) && (floorf(m) == 0.0f);
      }
      bt[e] = res ? (uint8_t)1 : (uint8_t)0;
    }
    ((uchar4*)(strain + (size_t)t * PLANE_E))[idx] = make_uchar4(bt[0], bt[1], bt[2], bt[3]);
  }
}

__global__ __launch_bounds__(512) void step_kernel(
    const float* __restrict__ W, const float* __restrict__ thresholds,
    const uint8_t* __restrict__ strain,
    const uint8_t* __restrict__ buf_prev, uint8_t* __restrict__ buf_cur,
    float* __restrict__ memb, float* __restrict__ counts, float* __restrict__ out,
    int t, int c_lo) {
  __shared__ float sB[32][64];
  const int c  = c_lo + blockIdx.y;
  const int tid = threadIdx.x;
  const int to = tid & 15;
  const int tb = tid >> 4;
  const int o0 = blockIdx.x * 64;
  const float thr = thresholds[c];
  const uint8_t* Asrc = (c == 0) ? (strain + (size_t)t * PLANE_E)
                                 : (buf_prev + (size_t)(c - 1) * PLANE_E);
  const float* Wc = W + (size_t)c * NN * NN;
  float acc[8][4];
#pragma unroll
  for (int i = 0; i < 8; ++i)
#pragma unroll
    for (int j = 0; j < 4; ++j) acc[i][j] = 0.f;
  for (int k0 = 0; k0 < NN; k0 += 32) {
    {
      int row = tid >> 4;
      int col = (tid & 15) << 2;
      float4 wv = *(const float4*)(Wc + (size_t)(k0 + row) * NN + (o0 + col));
      *(float4*)&sB[row][col] = wv;
    }
    __syncthreads();
#pragma unroll
    for (int kk = 0; kk < 32; kk += 4) {
      float a[8][4];
#pragma unroll
      for (int bb = 0; bb < 8; ++bb) {
        uchar4 av = *(const uchar4*)(Asrc + (size_t)(tb * 8 + bb) * NN + (k0 + kk));
        a[bb][0] = (float)av.x; a[bb][1] = (float)av.y;
        a[bb][2] = (float)av.z; a[bb][3] = (float)av.w;
      }
#pragma unroll
      for (int j = 0; j < 4; ++j) {
        float4 w = *(const float4*)&sB[kk + j][to << 2];
#pragma unroll
        for (int bb = 0; bb < 8; ++bb) {
          acc[bb][0] = fmaf(a[bb][j], w.x, acc[bb][0]);
          acc[bb][1] = fmaf(a[bb][j], w.y, acc[bb][1]);
          acc[bb][2] = fmaf(a[bb][j], w.z, acc[bb][2]);
          acc[bb][3] = fmaf(a[bb][j], w.w, acc[bb][3]);
        }
      }
    }
    __syncthreads();
  }
  float*   membc = memb + (size_t)c * PLANE_E;
  uint8_t* bufc  = buf_cur + (size_t)c * PLANE_E;
#pragma unroll
  for (int bb = 0; bb < 8; ++bb) {
    int b = tb * 8 + bb;
    size_t idx = (size_t)b * NN + o0 + (to << 2);
    float4 m = *(float4*)(membc + idx);
    m.x += acc[bb][0]; m.y += acc[bb][1]; m.z += acc[bb][2]; m.w += acc[bb][3];
    uchar4 f;
    f.x = (thr < m.x) ? 1 : 0; f.y = (thr < m.y) ? 1 : 0;
    f.z = (thr < m.z) ? 1 : 0; f.w = (thr < m.w) ? 1 : 0;
    if (f.x) m.x -= thr;  if (f.y) m.y -= thr;
    if (f.z) m.z -= thr;  if (f.w) m.w -= thr;
    *(float4*)(membc + idx) = m;
    *(uchar4*)(bufc + idx) = f;
    if (c == NCORE - 1) {
      float4 cv = *(float4*)(counts + idx);
      cv.x += (float)f.x; cv.y += (float)f.y; cv.z += (float)f.z; cv.w += (float)f.w;
      if (t == TSIM + NCORE - 2) {
        *(float4*)(out + idx) = make_float4(cv.x * 0.03125f, cv.y * 0.03125f,
                                            cv.z * 0.03125f, cv.w * 0.03125f);
      } else {
        *(float4*)(counts + idx) = cv;
      }
    }
  }
}

extern "C" void kernel_launch(void* const* d_in, const int* in_sizes, int n_in,
                              void* d_out, int out_size, void* d_ws, size_t ws_size,
                              hipStream_t stream) {
  const float* x   = (const float*)d_in[0];
  const float* W   = (const float*)d_in[1];
  const float* thr = (const float*)d_in[2];
  float* out = (float*)d_out;
  uint8_t* ws = (uint8_t*)d_ws;

  constexpr size_t NEED = 268435456ull;  // memb+strain+buf0+buf1+Wh+Wm+Wl = 256 MiB
  if (ws_size >= NEED) {
    // layout: memb f32 (16.78M) | strain bf16 swz (33.55M) | buf0 (8.39M) | buf1 (8.39M)
    //         | Wh (67.1M) | Wm (67.1M) | Wl (67.1M)   — counts live in d_out
    float*   memb   = (float*)ws;
    uint8_t* strain = ws + 16777216;
    uint8_t* buf0   = ws + 50331648;
    uint8_t* buf1   = ws + 58720256;
    uint8_t* Wh     = ws + 67108864;
    uint8_t* Wm     = ws + 134217728;
    uint8_t* Wl     = ws + 201326592;

    zero_f32_kernel<<<dim3(4096), 256, 0, stream>>>(memb, 1048576);     // 4,194,304 f32
    zero_f32_kernel<<<dim3(512),  256, 0, stream>>>(out, 131072);       // 524,288 f32
    spikes_bf16_kernel<<<dim3(256), 256, 0, stream>>>(x, strain);
    wsplit_kernel<<<dim3(64, 32, 8), 256, 0, stream>>>(W, Wh, Wm, Wl);

    for (int t = 0; t < NSTEP; ++t) {
      int c_lo = (t > TSIM - 1) ? (t - (TSIM - 1)) : 0;
      int c_hi = (t < NCORE - 1) ? t : (NCORE - 1);
      uint8_t* prev = (t & 1) ? buf0 : buf1;
      uint8_t* cur  = (t & 1) ? buf1 : buf0;
      step_mfma_kernel<<<dim3(32, c_hi - c_lo + 1), 256, 0, stream>>>(
          Wh, Wm, Wl, thr, strain, prev, cur, memb, out, t, c_lo);
    }
  } else {
    // round-1 fallback (fits in 44 MB)
    float*   memb   = (float*)ws;
    float*   counts = (float*)(ws + (size_t)8 * PLANE_E * 4);
    uint8_t* strain = ws + (size_t)9 * PLANE_E * 4;
    uint8_t* buf0   = strain + (size_t)32 * PLANE_E;
    uint8_t* buf1   = buf0 + (size_t)8 * PLANE_E;
    int n4 = 9 * PLANE_E / 4;
    zero_f32_kernel<<<dim3(n4 / 256), 256, 0, stream>>>(memb, n4);
    spikes_kernel<<<dim3(PLANE_E / 4 / 256), 256, 0, stream>>>(x, strain);
    for (int t = 0; t < NSTEP; ++t) {
      int c_lo = (t > TSIM - 1) ? (t - (TSIM - 1)) : 0;
      int c_hi = (t < NCORE - 1) ? t : (NCORE - 1);
      uint8_t* prev = (t & 1) ? buf0 : buf1;
      uint8_t* cur  = (t & 1) ? buf1 : buf0;
      step_kernel<<<dim3(32, c_hi - c_lo + 1), 512, 0, stream>>>(
          W, thr, strain, prev, cur, memb, counts, out, t, c_lo);
    }
  }
}

// Round 3
// 2491.030 us; speedup vs baseline: 4.1781x; 1.0632x over previous
//
#include <hip/hip_runtime.h>
#include <hip/hip_fp16.h>
#include <stdint.h>

#define BB 256
#define NN 2048
#define NCORE 8
#define TSIM 32
#define NSTEP 39
#define PLANE_E (BB*NN)        // 524288 elements
#define PLANE_H (PLANE_E*2)    // 1 MiB fp16 plane
#define ROWB (NN*2)            // 4096 B per row (fp16)

typedef _Float16 h8v __attribute__((ext_vector_type(8)));
typedef float f4v __attribute__((ext_vector_type(4)));

__device__ __forceinline__ void load_lds16(const void* g, void* l) {
  __builtin_amdgcn_global_load_lds((const __attribute__((address_space(1))) void*)g,
                                   (__attribute__((address_space(3))) void*)l, 16, 0, 0);
}

// ---------------- zero init ----------------
__global__ void zero_f32_kernel(float* __restrict__ p, int n4) {
  int i = blockIdx.x * 256 + threadIdx.x;
  if (i < n4) ((float4*)p)[i] = make_float4(0.f, 0.f, 0.f, 0.f);
}

// ---------------- spike trains, fp16 (1.0), swizzled A layout ----------------
// byte(b,k) = b*4096 + (k>>5)*64 + ((((k>>3)&3) ^ ((b>>1)&3))<<4) + (k&7)*2
__global__ void spikes_h_kernel(const float* __restrict__ x, uint8_t* __restrict__ strain) {
  int t = blockIdx.x * 256 + threadIdx.x;    // over BB*NN/8
  int b = t >> 8;
  int oct = t & 255;                         // k-octet index
  const float* xp = x + (size_t)b * NN + oct * 8;
  float nsf[8], sp[8]; int ns[8];
#pragma unroll
  for (int e = 0; e < 8; ++e) {
    float nv = rintf(xp[e] * 32.0f);
    nsf[e] = nv; ns[e] = (int)nv; sp[e] = 32.0f / fmaxf(nv, 1.0f);
  }
  uint32_t base = (uint32_t)b * ROWB + ((uint32_t)(oct >> 2) << 6)
                + ((uint32_t)((oct & 3) ^ ((b >> 1) & 3)) << 4);
  for (int cyc = 0; cyc < TSIM; ++cyc) {
    float ct = (float)cyc;
    uint16_t v[8];
#pragma unroll
    for (int e = 0; e < 8; ++e) {
      bool res;
      if (ns[e] == TSIM)      res = true;
      else if (ns[e] == 0)    res = false;
      else {
        float q = floorf(ct / sp[e]);
        float m = fmodf(ct, sp[e]);
        res = (q < nsf[e]) && (floorf(m) == 0.0f);
      }
      v[e] = res ? (uint16_t)0x3C00 : (uint16_t)0;   // fp16 1.0
    }
    uint4 pk;
    pk.x = (uint32_t)v[0] | ((uint32_t)v[1] << 16);
    pk.y = (uint32_t)v[2] | ((uint32_t)v[3] << 16);
    pk.z = (uint32_t)v[4] | ((uint32_t)v[5] << 16);
    pk.w = (uint32_t)v[6] | ((uint32_t)v[7] << 16);
    *(uint4*)(strain + (size_t)cyc * PLANE_H + base) = pk;
  }
}

// ---------------- W split: fp16 2-term, LDS-free, swizzled chunk layout ----------------
// Whm chunk id = ((c*32 + nt64)*64 + ks), 8192 B each:
//   [h(0/1)][plane(0/1)][n''(0..31)][slot(0..3)*16B], slot = kq ^ ((n'>>1)&3), n' = h*32+n''
__global__ __launch_bounds__(256) void wsplit_kernel(const float* __restrict__ W,
                                                     uint8_t* __restrict__ Whm) {
  int ks = blockIdx.x, nt = blockIdx.y, c = blockIdx.z;
  int tid = threadIdx.x;
  int kq = tid >> 6, np = tid & 63;
  const float* src = W + (((size_t)c * NN) + (size_t)(ks * 32 + kq * 8)) * NN + nt * 64 + np;
  uint16_t hv[8], mv[8];
#pragma unroll
  for (int e = 0; e < 8; ++e) {
    float w = src[(size_t)e * NN];
    uint16_t h; float hf;
    if (fabsf(w) < 6.103515625e-05f) { h = 0; hf = 0.f; }        // avoid fp16-subnormal hi
    else { __half hh = __float2half_rz(w); h = __half_as_ushort(hh); hf = __half2float(hh); }
    float r1 = w - hf;                                           // exact
    mv[e] = __half_as_ushort(__float2half_rn(r1 * 2048.0f));     // normal-range mid
    hv[e] = h;
  }
  uint4 hp, mp;
  hp.x = (uint32_t)hv[0] | ((uint32_t)hv[1] << 16);
  hp.y = (uint32_t)hv[2] | ((uint32_t)hv[3] << 16);
  hp.z = (uint32_t)hv[4] | ((uint32_t)hv[5] << 16);
  hp.w = (uint32_t)hv[6] | ((uint32_t)hv[7] << 16);
  mp.x = (uint32_t)mv[0] | ((uint32_t)mv[1] << 16);
  mp.y = (uint32_t)mv[2] | ((uint32_t)mv[3] << 16);
  mp.z = (uint32_t)mv[4] | ((uint32_t)mv[5] << 16);
  mp.w = (uint32_t)mv[6] | ((uint32_t)mv[7] << 16);
  size_t chunkbase = (((size_t)c * 32 + nt) * 64 + ks) * 8192;
  int h = np >> 5, n2 = np & 31, slot = kq ^ ((np >> 1) & 3);
  size_t off = chunkbase + (size_t)h * 4096 + n2 * 64 + slot * 16;
  *(uint4*)(Whm + off)        = hp;
  *(uint4*)(Whm + off + 2048) = mp;
}

// ---------------- one pipeline step (template on BN) ----------------
// grid (2048/BN n-tiles, active cores), 256 threads (4 waves).
template<int BN>
__global__ __launch_bounds__(256) void step_mfma_kernel(
    const uint8_t* __restrict__ Whm, const float* __restrict__ thresholds,
    const uint8_t* __restrict__ strain,
    const uint8_t* __restrict__ buf_prev, uint8_t* __restrict__ buf_cur,
    float* __restrict__ memb, float* __restrict__ out, int t, int c_lo) {
  constexpr int MI   = (BN == 64) ? 8 : 4;       // m-fragments per wave
  constexpr int BSZ  = BN * 128;                  // B bytes per chunk (2 planes)
  constexpr int CLST = BN + ((BN == 64) ? 8 : 4); // padded epilogue stride
  constexpr int NHALF = (BN == 64) ? 2 : 4;
  constexpr int RPH   = 256 / NHALF;              // rows per epilogue phase
  __shared__ uint8_t smem[32768 + 2 * BSZ];       // A 2x16K | B 2xBSZ; epilogue overlay

  const int tid = threadIdx.x;
  const int nt = blockIdx.x;
  const int c = c_lo + blockIdx.y;
  const int l = tid & 63, wid = tid >> 6;
  const int wm = (BN == 64) ? (wid >> 1) : wid;
  const int wn = (BN == 64) ? (wid & 1) : 0;
  const int lr = l & 15, lh = l >> 4;

  const uint8_t* Asrc = (c == 0) ? (strain + (size_t)t * PLANE_H)
                                 : (buf_prev + (size_t)(c - 1) * PLANE_H);
  const uint8_t* asrcb = Asrc + (size_t)(tid >> 2) * ROWB + (tid & 3) * 16;
  const int nt64 = (BN == 64) ? nt : (nt >> 1);
  const uint8_t* wsrc = Whm + (((size_t)c * 32 + nt64) * 64) * 8192 + (size_t)tid * 16
                      + ((BN == 32) ? (size_t)(nt & 1) * 4096 : 0);

  // fragment LDS byte offsets (swizzle phase invariant under +16 rows)
  const int R0 = wm * (MI * 16) + lr;
  const uint32_t aoff = (uint32_t)R0 * 64 + ((uint32_t)(lh ^ ((R0 >> 1) & 3)) << 4);
  const int N0a = wn * 32 + lr;
  const int N0b = wn * 32 + 16 + lr;
  const uint32_t boff0 = (uint32_t)(N0a >> 5) * 4096 + (uint32_t)(N0a & 31) * 64
                       + ((uint32_t)(lh ^ ((N0a >> 1) & 3)) << 4);
  const uint32_t boff1 = (uint32_t)(N0b >> 5) * 4096 + (uint32_t)(N0b & 31) * 64
                       + ((uint32_t)(lh ^ ((N0b >> 1) & 3)) << 4);

  f4v acch[MI][2], accm[MI][2];
  const f4v fzero = {0.f, 0.f, 0.f, 0.f};
#pragma unroll
  for (int mi = 0; mi < MI; ++mi) {
    acch[mi][0] = fzero; acch[mi][1] = fzero;
    accm[mi][0] = fzero; accm[mi][1] = fzero;
  }

#define ISSUE(nch) do { \
    uint8_t* Ad_ = smem + ((nch) & 1) * 16384; \
    uint8_t* Bd_ = smem + 32768 + ((nch) & 1) * BSZ; \
    load_lds16(asrcb + 0 * 262144 + (nch) * 64, Ad_ + 0 * 4096 + tid * 16); \
    load_lds16(asrcb + 1 * 262144 + (nch) * 64, Ad_ + 1 * 4096 + tid * 16); \
    load_lds16(asrcb + 2 * 262144 + (nch) * 64, Ad_ + 2 * 4096 + tid * 16); \
    load_lds16(asrcb + 3 * 262144 + (nch) * 64, Ad_ + 3 * 4096 + tid * 16); \
    if constexpr (BN == 64) { \
      load_lds16(wsrc + (size_t)(nch) * 8192,        Bd_ + tid * 16); \
      load_lds16(wsrc + (size_t)(nch) * 8192 + 4096, Bd_ + 4096 + tid * 16); \
    } else { \
      load_lds16(wsrc + (size_t)(nch) * 8192, Bd_ + tid * 16); \
    } \
  } while (0)

  ISSUE(0);
  for (int k = 0; k < 64; ++k) {
    asm volatile("s_waitcnt lgkmcnt(0)" ::: "memory");   // our LDS reads done pre-barrier
    __builtin_amdgcn_s_barrier();                        // A: prev buffer free to overwrite
    if (k < 63) {
      ISSUE(k + 1);
      if constexpr (BN == 64) asm volatile("s_waitcnt vmcnt(6)" ::: "memory");
      else                    asm volatile("s_waitcnt vmcnt(5)" ::: "memory");
    } else {
      asm volatile("s_waitcnt vmcnt(0)" ::: "memory");
    }
    __builtin_amdgcn_s_barrier();                        // B: chunk k landed everywhere
    const uint8_t* Ab = smem + (k & 1) * 16384;
    const uint8_t* Bb = smem + 32768 + (k & 1) * BSZ;
    h8v bh0 = *(const h8v*)(Bb + boff0);
    h8v bm0 = *(const h8v*)(Bb + boff0 + 2048);
    h8v bh1 = *(const h8v*)(Bb + boff1);
    h8v bm1 = *(const h8v*)(Bb + boff1 + 2048);
#pragma unroll
    for (int mi = 0; mi < MI; ++mi) {
      h8v a = *(const h8v*)(Ab + aoff + mi * 1024);
      acch[mi][0] = __builtin_amdgcn_mfma_f32_16x16x32_f16(a, bh0, acch[mi][0], 0, 0, 0);
      accm[mi][0] = __builtin_amdgcn_mfma_f32_16x16x32_f16(a, bm0, accm[mi][0], 0, 0, 0);
      acch[mi][1] = __builtin_amdgcn_mfma_f32_16x16x32_f16(a, bh1, acch[mi][1], 0, 0, 0);
      accm[mi][1] = __builtin_amdgcn_mfma_f32_16x16x32_f16(a, bm1, accm[mi][1], 0, 0, 0);
    }
  }
#undef ISSUE

  // ---- epilogue: combine terms, LDS transpose, membrane update ----
  const float thr = thresholds[c];
  float* Cl = (float*)smem;
  const int o0 = nt * BN;
  float* membp = memb + (size_t)c * PLANE_E;
  uint8_t* bufc = buf_cur + (size_t)c * PLANE_H;
  const bool last = (t == NSTEP - 1);
#pragma unroll
  for (int half = 0; half < NHALF; ++half) {
    __syncthreads();
    if (wm == half) {
#pragma unroll
      for (int mi = 0; mi < MI; ++mi)
#pragma unroll
        for (int nj = 0; nj < 2; ++nj)
#pragma unroll
          for (int rg = 0; rg < 4; ++rg)
            Cl[(mi * 16 + lh * 4 + rg) * CLST + wn * 32 + nj * 16 + lr] =
                fmaf(accm[mi][nj][rg], 0x1p-11f, acch[mi][nj][rg]);
    }
    __syncthreads();
    constexpr int NP = (RPH * BN) / 1024;   // float4s per thread (8 or 2)
#pragma unroll
    for (int p = 0; p < NP; ++p) {
      int rr, c4;
      if constexpr (BN == 64) { rr = p * 16 + (tid >> 4); c4 = (tid & 15) * 4; }
      else                    { rr = p * 32 + (tid >> 3); c4 = (tid & 7) * 4; }
      int b = half * RPH + rr;
      int o = o0 + c4;
      float4 d = *(const float4*)&Cl[rr * CLST + c4];
      size_t idx = (size_t)b * NN + o;
      float4 mvv = *(float4*)(membp + idx);
      mvv.x += d.x; mvv.y += d.y; mvv.z += d.z; mvv.w += d.w;
      bool g0 = thr < mvv.x, g1 = thr < mvv.y, g2 = thr < mvv.z, g3 = thr < mvv.w;
      if (g0) mvv.x -= thr;  if (g1) mvv.y -= thr;
      if (g2) mvv.z -= thr;  if (g3) mvv.w -= thr;
      *(float4*)(membp + idx) = mvv;
      uint32_t ba = (uint32_t)b * ROWB + ((uint32_t)(o >> 5) << 6)
                  + ((uint32_t)(((o >> 3) & 3) ^ ((b >> 1) & 3)) << 4) + ((o & 7) << 1);
      uint2 pk;
      pk.x = (g0 ? 0x3C00u : 0u) | ((g1 ? 0x3C00u : 0u) << 16);
      pk.y = (g2 ? 0x3C00u : 0u) | ((g3 ? 0x3C00u : 0u) << 16);
      *(uint2*)(bufc + ba) = pk;
      if (c == NCORE - 1) {
        float4 cv = *(float4*)(out + idx);
        cv.x += g0 ? 1.f : 0.f; cv.y += g1 ? 1.f : 0.f;
        cv.z += g2 ? 1.f : 0.f; cv.w += g3 ? 1.f : 0.f;
        if (last) { cv.x *= 0.03125f; cv.y *= 0.03125f; cv.z *= 0.03125f; cv.w *= 0.03125f; }
        *(float4*)(out + idx) = cv;
      }
    }
  }
}

extern "C" void kernel_launch(void* const* d_in, const int* in_sizes, int n_in,
                              void* d_out, int out_size, void* d_ws, size_t ws_size,
                              hipStream_t stream) {
  const float* x   = (const float*)d_in[0];
  const float* W   = (const float*)d_in[1];
  const float* thr = (const float*)d_in[2];
  float* out = (float*)d_out;
  uint8_t* ws = (uint8_t*)d_ws;

  // layout: memb f32 16.78M | strain fp16 33.55M | buf0 8.39M | buf1 8.39M | Whm 134.2M
  constexpr size_t NEED = 201326592ull;   // 192 MiB
  if (ws_size < NEED) return;             // (round-2 proved ws_size >= 256 MiB)
  float*   memb   = (float*)ws;
  uint8_t* strain = ws + 16777216;
  uint8_t* buf0   = ws + 50331648;
  uint8_t* buf1   = ws + 58720256;
  uint8_t* Whm    = ws + 67108864;

  zero_f32_kernel<<<dim3(4096), 256, 0, stream>>>(memb, 1048576);   // 4,194,304 f32
  zero_f32_kernel<<<dim3(512),  256, 0, stream>>>(out, 131072);     // 524,288 f32
  spikes_h_kernel<<<dim3(256), 256, 0, stream>>>(x, strain);
  wsplit_kernel<<<dim3(64, 32, 8), 256, 0, stream>>>(W, Whm);

  for (int t = 0; t < NSTEP; ++t) {
    int c_lo = (t > TSIM - 1) ? (t - (TSIM - 1)) : 0;
    int c_hi = (t < NCORE - 1) ? t : (NCORE - 1);
    int nc = c_hi - c_lo + 1;
    uint8_t* prev = (t & 1) ? buf0 : buf1;
    uint8_t* cur  = (t & 1) ? buf1 : buf0;
    if (nc <= 4) {
      step_mfma_kernel<32><<<dim3(64, nc), 256, 0, stream>>>(
          Whm, thr, strain, prev, cur, memb, out, t, c_lo);
    } else {
      step_mfma_kernel<64><<<dim3(32, nc), 256, 0, stream>>>(
          Whm, thr, strain, prev, cur, memb, out, t, c_lo);
    }
  }
}

// Round 4
// 1551.487 us; speedup vs baseline: 6.7083x; 1.6056x over previous
//
#include <hip/hip_runtime.h>
#include <hip/hip_fp16.h>
#include <stdint.h>

#define BB 256
#define NN 2048
#define NCORE 8
#define TSIM 32
#define NSTEP 39
#define PLANE_E (BB*NN)        // 524288 elements
#define PLANE_H (PLANE_E*2)    // 1 MiB fp16 plane
#define ROWB (NN*2)            // 4096 B per row (fp16)

typedef _Float16 h8v __attribute__((ext_vector_type(8)));
typedef float f4v __attribute__((ext_vector_type(4)));

__device__ __forceinline__ void load_lds16(const void* g, void* l) {
  __builtin_amdgcn_global_load_lds((const __attribute__((address_space(1))) void*)g,
                                   (__attribute__((address_space(3))) void*)l, 16, 0, 0);
}

// ---------------- zero init ----------------
__global__ void zero_f32_kernel(float* __restrict__ p, int n4) {
  int i = blockIdx.x * 256 + threadIdx.x;
  if (i < n4) ((float4*)p)[i] = make_float4(0.f, 0.f, 0.f, 0.f);
}

// ---------------- spike trains, fp16 (1.0), swizzled A layout ----------------
// byte(b,k) = b*4096 + (k>>5)*64 + ((((k>>3)&3) ^ ((b>>1)&3))<<4) + (k&7)*2
__global__ void spikes_h_kernel(const float* __restrict__ x, uint8_t* __restrict__ strain) {
  int t = blockIdx.x * 256 + threadIdx.x;    // over BB*NN/8
  int b = t >> 8;
  int oct = t & 255;                         // k-octet index
  const float* xp = x + (size_t)b * NN + oct * 8;
  float nsf[8], sp[8]; int ns[8];
#pragma unroll
  for (int e = 0; e < 8; ++e) {
    float nv = rintf(xp[e] * 32.0f);
    nsf[e] = nv; ns[e] = (int)nv; sp[e] = 32.0f / fmaxf(nv, 1.0f);
  }
  uint32_t base = (uint32_t)b * ROWB + ((uint32_t)(oct >> 2) << 6)
                + ((uint32_t)((oct & 3) ^ ((b >> 1) & 3)) << 4);
  for (int cyc = 0; cyc < TSIM; ++cyc) {
    float ct = (float)cyc;
    uint16_t v[8];
#pragma unroll
    for (int e = 0; e < 8; ++e) {
      bool res;
      if (ns[e] == TSIM)      res = true;
      else if (ns[e] == 0)    res = false;
      else {
        float q = floorf(ct / sp[e]);
        float m = fmodf(ct, sp[e]);
        res = (q < nsf[e]) && (floorf(m) == 0.0f);
      }
      v[e] = res ? (uint16_t)0x3C00 : (uint16_t)0;   // fp16 1.0
    }
    uint4 pk;
    pk.x = (uint32_t)v[0] | ((uint32_t)v[1] << 16);
    pk.y = (uint32_t)v[2] | ((uint32_t)v[3] << 16);
    pk.z = (uint32_t)v[4] | ((uint32_t)v[5] << 16);
    pk.w = (uint32_t)v[6] | ((uint32_t)v[7] << 16);
    *(uint4*)(strain + (size_t)cyc * PLANE_H + base) = pk;
  }
}

// ---------------- W split: fp16 2-term, swizzled chunk layout ----------------
// Whm chunk id = ((c*32 + nt64)*64 + ks), 8192 B: [h][plane][n2][slot*16]
// slot = kq ^ ((n'>>1)&3), n' = h*32+n2
__global__ __launch_bounds__(256) void wsplit_kernel(const float* __restrict__ W,
                                                     uint8_t* __restrict__ Whm) {
  int ks = blockIdx.x, nt = blockIdx.y, c = blockIdx.z;
  int tid = threadIdx.x;
  int kq = tid >> 6, np = tid & 63;
  const float* src = W + (((size_t)c * NN) + (size_t)(ks * 32 + kq * 8)) * NN + nt * 64 + np;
  uint16_t hv[8], mv[8];
#pragma unroll
  for (int e = 0; e < 8; ++e) {
    float w = src[(size_t)e * NN];
    uint16_t h; float hf;
    if (fabsf(w) < 6.103515625e-05f) { h = 0; hf = 0.f; }        // avoid fp16-subnormal hi
    else { __half hh = __float2half_rz(w); h = __half_as_ushort(hh); hf = __half2float(hh); }
    float r1 = w - hf;                                           // exact
    mv[e] = __half_as_ushort(__float2half_rn(r1 * 2048.0f));     // normal-range mid
    hv[e] = h;
  }
  uint4 hp, mp;
  hp.x = (uint32_t)hv[0] | ((uint32_t)hv[1] << 16);
  hp.y = (uint32_t)hv[2] | ((uint32_t)hv[3] << 16);
  hp.z = (uint32_t)hv[4] | ((uint32_t)hv[5] << 16);
  hp.w = (uint32_t)hv[6] | ((uint32_t)hv[7] << 16);
  mp.x = (uint32_t)mv[0] | ((uint32_t)mv[1] << 16);
  mp.y = (uint32_t)mv[2] | ((uint32_t)mv[3] << 16);
  mp.z = (uint32_t)mv[4] | ((uint32_t)mv[5] << 16);
  mp.w = (uint32_t)mv[6] | ((uint32_t)mv[7] << 16);
  size_t chunkbase = (((size_t)c * 32 + nt) * 64 + ks) * 8192;
  int h = np >> 5, n2 = np & 31, slot = kq ^ ((np >> 1) & 3);
  size_t off = chunkbase + (size_t)h * 4096 + n2 * 64 + slot * 16;
  *(uint4*)(Whm + off)        = hp;
  *(uint4*)(Whm + off + 2048) = mp;
}

// ---------------- one pipeline step: 8 waves, BK=64, depth-3 pipeline ----------------
// grid (active cores, 2048/BN n-tiles), 512 threads.
template<int BN>
__global__ __launch_bounds__(512) void step_mfma_kernel(
    const uint8_t* __restrict__ Whm, const float* __restrict__ thresholds,
    const uint8_t* __restrict__ strain,
    const uint8_t* __restrict__ buf_prev, uint8_t* __restrict__ buf_cur,
    float* __restrict__ memb, float* __restrict__ out, int t, int c_lo) {
  constexpr int BCH = (BN == 64) ? 16384 : 8192;   // B bytes per BK=64 chunk
  constexpr int LPC = (BN == 64) ? 6 : 5;          // DMA loads/thread/chunk
  constexpr int MI  = (BN == 64) ? 4 : 2;          // 16-row frags per wave
  constexpr int CLST = BN + 4;
  __shared__ uint8_t smem[3 * 32768 + 3 * BCH];

  const int tid = threadIdx.x;
  const int c  = c_lo + blockIdx.x;                // x = core -> XCD = core for nc=8
  const int nt = blockIdx.y;
  const int l = tid & 63, wid = tid >> 6;
  const int wm = (BN == 64) ? (wid >> 1) : wid;
  const int wn = (BN == 64) ? (wid & 1) : 0;
  const int lr = l & 15, lh = l >> 4;
  uint8_t* As = smem;
  uint8_t* Bs = smem + 3 * 32768;

  const uint8_t* Asrc = (c == 0) ? (strain + (size_t)t * PLANE_H)
                                 : (buf_prev + (size_t)(c - 1) * PLANE_H);
  const uint8_t* ab[4];
#pragma unroll
  for (int j = 0; j < 4; ++j) {
    int i = j * 512 + tid;
    ab[j] = Asrc + (size_t)(i >> 3) * 4096 + (i & 7) * 16;
  }
  const size_t wbase = (((size_t)c * 32 + ((BN == 64) ? nt : (nt >> 1))) * 64) * 8192;
  const uint8_t* bb0;
  const uint8_t* bb1;
  if constexpr (BN == 64) {
    bb0 = Whm + wbase + (size_t)tid * 16;
    bb1 = Whm + wbase + (size_t)(512 + tid) * 16;
  } else {
    bb0 = Whm + wbase + (size_t)(tid >> 8) * 8192 + (size_t)(nt & 1) * 4096
        + (size_t)(tid & 255) * 16;
    bb1 = bb0;
  }

  // fragment LDS byte offsets
  const uint32_t swz = (uint32_t)(lh ^ ((lr >> 1) & 3)) << 4;
  const uint32_t base_aoff = (uint32_t)(wm * (MI * 16) + lr) * 128 + swz;
  const uint32_t base_boff = ((BN == 64) ? (uint32_t)wn * 4096 : 0u) + (uint32_t)lr * 64 + swz;

  f4v acch[MI][2], accm[MI][2];
  const f4v fzero = {0.f, 0.f, 0.f, 0.f};
#pragma unroll
  for (int mi = 0; mi < MI; ++mi) {
    acch[mi][0] = fzero; acch[mi][1] = fzero;
    accm[mi][0] = fzero; accm[mi][1] = fzero;
  }

  auto issue = [&](int kk, int slot) {
    uint8_t* Ad = As + slot * 32768;
    uint8_t* Bd = Bs + slot * BCH;
#pragma unroll
    for (int j = 0; j < 4; ++j)
      load_lds16(ab[j] + kk * 128, Ad + (j * 512 + tid) * 16);
    if constexpr (BN == 64) {
      load_lds16(bb0 + (size_t)kk * 16384, Bd + tid * 16);
      load_lds16(bb1 + (size_t)kk * 16384, Bd + 8192 + tid * 16);
    } else {
      load_lds16(bb0 + (size_t)kk * 16384, Bd + tid * 16);
    }
  };

  auto comp = [&](int slot) {
    const uint8_t* Ab = As + slot * 32768;
    const uint8_t* Bb = Bs + slot * BCH;
#pragma unroll
    for (int ks = 0; ks < 2; ++ks) {
      h8v bh[2], bm[2];
#pragma unroll
      for (int nj = 0; nj < 2; ++nj) {
        uint32_t bo = base_boff + nj * 1024 + ks * ((BN == 64) ? 8192 : 4096);
        bh[nj] = *(const h8v*)(Bb + bo);
        bm[nj] = *(const h8v*)(Bb + bo + 2048);
      }
#pragma unroll
      for (int mi = 0; mi < MI; ++mi) {
        h8v a = *(const h8v*)(Ab + base_aoff + mi * 2048 + ks * 64);
        acch[mi][0] = __builtin_amdgcn_mfma_f32_16x16x32_f16(a, bh[0], acch[mi][0], 0, 0, 0);
        acch[mi][1] = __builtin_amdgcn_mfma_f32_16x16x32_f16(a, bh[1], acch[mi][1], 0, 0, 0);
        accm[mi][0] = __builtin_amdgcn_mfma_f32_16x16x32_f16(a, bm[0], accm[mi][0], 0, 0, 0);
        accm[mi][1] = __builtin_amdgcn_mfma_f32_16x16x32_f16(a, bm[1], accm[mi][1], 0, 0, 0);
      }
    }
  };

#define WAITV(n) asm volatile("s_waitcnt vmcnt(" #n ")" ::: "memory")
#define BAR() do { __builtin_amdgcn_s_barrier(); __builtin_amdgcn_sched_barrier(0); } while (0)
#define WAITLPC() do { if constexpr (BN == 64) WAITV(6); else WAITV(5); } while (0)

  issue(0, 0); issue(1, 1);
  WAITLPC(); BAR();
  for (int k = 0; k < 30; k += 3) {
    issue(k + 2, 2); comp(0);
    WAITLPC(); BAR();
    issue(k + 3, 0); comp(1);
    WAITLPC(); BAR();
    issue(k + 4, 1); comp(2);
    WAITLPC(); BAR();
  }
  comp(0);            // chunk 30
  WAITV(0); BAR();
  comp(1);            // chunk 31
#undef WAITV
#undef WAITLPC
#undef BAR

  // ---- epilogue: combine terms, LDS transpose, membrane update ----
  __syncthreads();
  const float thr = thresholds[c];
  float* Cl = (float*)smem;
#pragma unroll
  for (int mi = 0; mi < MI; ++mi)
#pragma unroll
    for (int nj = 0; nj < 2; ++nj)
#pragma unroll
      for (int rg = 0; rg < 4; ++rg) {
        int row = wm * (MI * 16) + mi * 16 + lh * 4 + rg;
        int col = wn * 32 + nj * 16 + lr;
        Cl[row * CLST + col] = fmaf(accm[mi][nj][rg], 0x1p-11f, acch[mi][nj][rg]);
      }
  __syncthreads();

  const int o0 = nt * BN;
  float* membp = memb + (size_t)c * PLANE_E;
  uint8_t* bufc = buf_cur + (size_t)c * PLANE_H;
  const bool last = (t == NSTEP - 1);
  constexpr int NP = (256 * BN) / (512 * 4);   // 8 (BN64) or 4 (BN32)
#pragma unroll
  for (int p = 0; p < NP; ++p) {
    int rr, c4;
    if constexpr (BN == 64) { rr = p * 32 + (tid >> 4); c4 = (tid & 15) * 4; }
    else                    { rr = p * 64 + (tid >> 3); c4 = (tid & 7) * 4; }
    int o = o0 + c4;
    float4 d = *(const float4*)&Cl[rr * CLST + c4];
    size_t idx = (size_t)rr * NN + o;
    float4 mvv = *(float4*)(membp + idx);
    mvv.x += d.x; mvv.y += d.y; mvv.z += d.z; mvv.w += d.w;
    bool g0 = thr < mvv.x, g1 = thr < mvv.y, g2 = thr < mvv.z, g3 = thr < mvv.w;
    if (g0) mvv.x -= thr;  if (g1) mvv.y -= thr;
    if (g2) mvv.z -= thr;  if (g3) mvv.w -= thr;
    *(float4*)(membp + idx) = mvv;
    uint32_t ba = (uint32_t)rr * ROWB + ((uint32_t)(o >> 5) << 6)
                + ((uint32_t)(((o >> 3) & 3) ^ ((rr >> 1) & 3)) << 4) + ((o & 7) << 1);
    uint2 pk;
    pk.x = (g0 ? 0x3C00u : 0u) | ((g1 ? 0x3C00u : 0u) << 16);
    pk.y = (g2 ? 0x3C00u : 0u) | ((g3 ? 0x3C00u : 0u) << 16);
    *(uint2*)(bufc + ba) = pk;
    if (c == NCORE - 1) {
      float4 cv = *(float4*)(out + idx);
      cv.x += g0 ? 1.f : 0.f; cv.y += g1 ? 1.f : 0.f;
      cv.z += g2 ? 1.f : 0.f; cv.w += g3 ? 1.f : 0.f;
      if (last) { cv.x *= 0.03125f; cv.y *= 0.03125f; cv.z *= 0.03125f; cv.w *= 0.03125f; }
      *(float4*)(out + idx) = cv;
    }
  }
}

extern "C" void kernel_launch(void* const* d_in, const int* in_sizes, int n_in,
                              void* d_out, int out_size, void* d_ws, size_t ws_size,
                              hipStream_t stream) {
  const float* x   = (const float*)d_in[0];
  const float* W   = (const float*)d_in[1];
  const float* thr = (const float*)d_in[2];
  float* out = (float*)d_out;
  uint8_t* ws = (uint8_t*)d_ws;

  // layout: memb f32 16.78M | strain fp16 33.55M | buf0 8.39M | buf1 8.39M | Whm 134.2M
  float*   memb   = (float*)ws;
  uint8_t* strain = ws + 16777216;
  uint8_t* buf0   = ws + 50331648;
  uint8_t* buf1   = ws + 58720256;
  uint8_t* Whm    = ws + 67108864;

  zero_f32_kernel<<<dim3(4096), 256, 0, stream>>>(memb, 1048576);
  zero_f32_kernel<<<dim3(512),  256, 0, stream>>>(out, 131072);
  spikes_h_kernel<<<dim3(256), 256, 0, stream>>>(x, strain);
  wsplit_kernel<<<dim3(64, 32, 8), 256, 0, stream>>>(W, Whm);

  for (int t = 0; t < NSTEP; ++t) {
    int c_lo = (t > TSIM - 1) ? (t - (TSIM - 1)) : 0;
    int c_hi = (t < NCORE - 1) ? t : (NCORE - 1);
    int nc = c_hi - c_lo + 1;
    uint8_t* prev = (t & 1) ? buf0 : buf1;
    uint8_t* cur  = (t & 1) ? buf1 : buf0;
    if (nc <= 4) {
      step_mfma_kernel<32><<<dim3(nc, 64), 512, 0, stream>>>(
          Whm, thr, strain, prev, cur, memb, out, t, c_lo);
    } else {
      step_mfma_kernel<64><<<dim3(nc, 32), 512, 0, stream>>>(
          Whm, thr, strain, prev, cur, memb, out, t, c_lo);
    }
  }
}

// Round 5
// 1524.880 us; speedup vs baseline: 6.8253x; 1.0174x over previous
//
#include <hip/hip_runtime.h>
#include <hip/hip_fp16.h>
#include <stdint.h>

#define BB 256
#define NN 2048
#define NCORE 8
#define TSIM 32
#define NSTEP 39
#define PLANE_E (BB*NN)        // 524288 elements
#define PLANE_H (PLANE_E*2)    // 1 MiB fp16 plane
#define ROWB (NN*2)            // 4096 B per row (fp16)

typedef _Float16 h8v __attribute__((ext_vector_type(8)));
typedef float f4v __attribute__((ext_vector_type(4)));

__device__ __forceinline__ void load_lds16(const void* g, void* l) {
  __builtin_amdgcn_global_load_lds((const __attribute__((address_space(1))) void*)g,
                                   (__attribute__((address_space(3))) void*)l, 16, 0, 0);
}

// ---------------- zero init ----------------
__global__ void zero_f32_kernel(float* __restrict__ p, int n4) {
  int i = blockIdx.x * 256 + threadIdx.x;
  if (i < n4) ((float4*)p)[i] = make_float4(0.f, 0.f, 0.f, 0.f);
}

// ---------------- spike trains, fp16 (1.0), 3-bit-swizzled A layout ----------------
// byte(b,k) = b*4096 + (k>>6)*128 + ((((k>>3)&7) ^ (b&7))<<4) + (k&7)*2
__global__ void spikes_h_kernel(const float* __restrict__ x, uint8_t* __restrict__ strain) {
  int t = blockIdx.x * 256 + threadIdx.x;    // over BB*NN/8
  int b = t >> 8;
  int oct = t & 255;                         // k-octet index (k = oct*8 + e)
  const float* xp = x + (size_t)b * NN + oct * 8;
  float nsf[8], sp[8]; int ns[8];
#pragma unroll
  for (int e = 0; e < 8; ++e) {
    float nv = rintf(xp[e] * 32.0f);
    nsf[e] = nv; ns[e] = (int)nv; sp[e] = 32.0f / fmaxf(nv, 1.0f);
  }
  uint32_t base = (uint32_t)b * ROWB + ((uint32_t)(oct >> 3) << 7)
                + ((uint32_t)((oct & 7) ^ (b & 7)) << 4);
  for (int cyc = 0; cyc < TSIM; ++cyc) {
    float ct = (float)cyc;
    uint16_t v[8];
#pragma unroll
    for (int e = 0; e < 8; ++e) {
      bool res;
      if (ns[e] == TSIM)      res = true;
      else if (ns[e] == 0)    res = false;
      else {
        float q = floorf(ct / sp[e]);
        float m = fmodf(ct, sp[e]);
        res = (q < nsf[e]) && (floorf(m) == 0.0f);
      }
      v[e] = res ? (uint16_t)0x3C00 : (uint16_t)0;   // fp16 1.0
    }
    uint4 pk;
    pk.x = (uint32_t)v[0] | ((uint32_t)v[1] << 16);
    pk.y = (uint32_t)v[2] | ((uint32_t)v[3] << 16);
    pk.z = (uint32_t)v[4] | ((uint32_t)v[5] << 16);
    pk.w = (uint32_t)v[6] | ((uint32_t)v[7] << 16);
    *(uint4*)(strain + (size_t)cyc * PLANE_H + base) = pk;
  }
}

// ---------------- W split: fp16 2-term, swizzled chunk layout (unchanged) ----------------
// Whm chunk id = ((c*32 + nt64)*64 + ks), 8192 B: [h][plane][n2][slot*16]
// slot = kq ^ ((n2>>1)&3)
__global__ __launch_bounds__(256) void wsplit_kernel(const float* __restrict__ W,
                                                     uint8_t* __restrict__ Whm) {
  int ks = blockIdx.x, nt = blockIdx.y, c = blockIdx.z;
  int tid = threadIdx.x;
  int kq = tid >> 6, np = tid & 63;
  const float* src = W + (((size_t)c * NN) + (size_t)(ks * 32 + kq * 8)) * NN + nt * 64 + np;
  uint16_t hv[8], mv[8];
#pragma unroll
  for (int e = 0; e < 8; ++e) {
    float w = src[(size_t)e * NN];
    uint16_t h; float hf;
    if (fabsf(w) < 6.103515625e-05f) { h = 0; hf = 0.f; }        // avoid fp16-subnormal hi
    else { __half hh = __float2half_rz(w); h = __half_as_ushort(hh); hf = __half2float(hh); }
    float r1 = w - hf;                                           // exact
    mv[e] = __half_as_ushort(__float2half_rn(r1 * 2048.0f));     // normal-range mid
    hv[e] = h;
  }
  uint4 hp, mp;
  hp.x = (uint32_t)hv[0] | ((uint32_t)hv[1] << 16);
  hp.y = (uint32_t)hv[2] | ((uint32_t)hv[3] << 16);
  hp.z = (uint32_t)hv[4] | ((uint32_t)hv[5] << 16);
  hp.w = (uint32_t)hv[6] | ((uint32_t)hv[7] << 16);
  mp.x = (uint32_t)mv[0] | ((uint32_t)mv[1] << 16);
  mp.y = (uint32_t)mv[2] | ((uint32_t)mv[3] << 16);
  mp.z = (uint32_t)mv[4] | ((uint32_t)mv[5] << 16);
  mp.w = (uint32_t)mv[6] | ((uint32_t)mv[7] << 16);
  size_t chunkbase = (((size_t)c * 32 + nt) * 64 + ks) * 8192;
  int h = np >> 5, n2 = np & 31, slot = kq ^ ((np >> 1) & 3);
  size_t off = chunkbase + (size_t)h * 4096 + n2 * 64 + slot * 16;
  *(uint4*)(Whm + off)        = hp;
  *(uint4*)(Whm + off + 2048) = mp;
}

// ---------------- one pipeline step: 8 waves, BK=64, depth-3 pipeline ----------------
// grid (active cores, 2048/BN n-tiles), 512 threads.
template<int BN>
__global__ __launch_bounds__(512) void step_mfma_kernel(
    const uint8_t* __restrict__ Whm, const float* __restrict__ thresholds,
    const uint8_t* __restrict__ strain,
    const uint8_t* __restrict__ buf_prev, uint8_t* __restrict__ buf_cur,
    float* __restrict__ memb, float* __restrict__ out, int t, int c_lo) {
  constexpr int BCH = (BN == 64) ? 16384 : 8192;   // B bytes per BK=64 chunk
  constexpr int MI  = (BN == 64) ? 4 : 2;          // 16-row frags per wave
  constexpr int CLST = BN + 4;
  __shared__ uint8_t smem[3 * 32768 + 3 * BCH];

  const int tid = threadIdx.x;
  const int c  = c_lo + blockIdx.x;                // x = core -> XCD = core for nc=8
  const int nt = blockIdx.y;
  const int l = tid & 63, wid = tid >> 6;
  const int wm = (BN == 64) ? (wid >> 1) : wid;
  const int wn = (BN == 64) ? (wid & 1) : 0;
  const int lr = l & 15, lh = l >> 4;
  uint8_t* As = smem;
  uint8_t* Bs = smem + 3 * 32768;

  const uint8_t* Asrc = (c == 0) ? (strain + (size_t)t * PLANE_H)
                                 : (buf_prev + (size_t)(c - 1) * PLANE_H);
  const uint8_t* ab[4];
#pragma unroll
  for (int j = 0; j < 4; ++j) {
    int i = j * 512 + tid;
    ab[j] = Asrc + (size_t)(i >> 3) * 4096 + (i & 7) * 16;
  }
  const size_t wbase = (((size_t)c * 32 + ((BN == 64) ? nt : (nt >> 1))) * 64) * 8192;
  const uint8_t* bb0;
  const uint8_t* bb1;
  if constexpr (BN == 64) {
    bb0 = Whm + wbase + (size_t)tid * 16;
    bb1 = Whm + wbase + (size_t)(512 + tid) * 16;
  } else {
    bb0 = Whm + wbase + (size_t)(tid >> 8) * 8192 + (size_t)(nt & 1) * 4096
        + (size_t)(tid & 255) * 16;
    bb1 = bb0;
  }

  // fragment LDS byte offsets
  // A: row-major 128 B rows, slot(3b) = (ks*4 + lh) ^ (row&7); ks=1 is ^64.
  const uint32_t base_aoff = (uint32_t)(wm * (MI * 16) + lr) * 128
                           + ((uint32_t)(lh ^ (lr & 7)) << 4);
  const uint32_t base_boff = ((BN == 64) ? (uint32_t)wn * 4096 : 0u) + (uint32_t)lr * 64
                           + ((uint32_t)(lh ^ ((lr >> 1) & 3)) << 4);

  f4v acch[MI][2], accm[MI][2];
  const f4v fzero = {0.f, 0.f, 0.f, 0.f};
#pragma unroll
  for (int mi = 0; mi < MI; ++mi) {
    acch[mi][0] = fzero; acch[mi][1] = fzero;
    accm[mi][0] = fzero; accm[mi][1] = fzero;
  }

  auto issue = [&](int kk, int slot) {
    uint8_t* Ad = As + slot * 32768;
    uint8_t* Bd = Bs + slot * BCH;
#pragma unroll
    for (int j = 0; j < 4; ++j)
      load_lds16(ab[j] + kk * 128, Ad + (j * 512 + tid) * 16);
    if constexpr (BN == 64) {
      load_lds16(bb0 + (size_t)kk * 16384, Bd + tid * 16);
      load_lds16(bb1 + (size_t)kk * 16384, Bd + 8192 + tid * 16);
    } else {
      load_lds16(bb0 + (size_t)kk * 16384, Bd + tid * 16);
    }
  };

  auto comp = [&](int slot) {
    const uint8_t* Ab = As + slot * 32768;
    const uint8_t* Bb = Bs + slot * BCH;
    __builtin_amdgcn_s_setprio(1);
#pragma unroll
    for (int ks = 0; ks < 2; ++ks) {
      h8v bh[2], bm[2];
#pragma unroll
      for (int nj = 0; nj < 2; ++nj) {
        uint32_t bo = base_boff + nj * 1024 + ks * ((BN == 64) ? 8192 : 4096);
        bh[nj] = *(const h8v*)(Bb + bo);
        bm[nj] = *(const h8v*)(Bb + bo + 2048);
      }
#pragma unroll
      for (int mi = 0; mi < MI; ++mi) {
        h8v a = *(const h8v*)(Ab + (base_aoff ^ (ks * 64)) + mi * 2048);
        acch[mi][0] = __builtin_amdgcn_mfma_f32_16x16x32_f16(a, bh[0], acch[mi][0], 0, 0, 0);
        acch[mi][1] = __builtin_amdgcn_mfma_f32_16x16x32_f16(a, bh[1], acch[mi][1], 0, 0, 0);
        accm[mi][0] = __builtin_amdgcn_mfma_f32_16x16x32_f16(a, bm[0], accm[mi][0], 0, 0, 0);
        accm[mi][1] = __builtin_amdgcn_mfma_f32_16x16x32_f16(a, bm[1], accm[mi][1], 0, 0, 0);
      }
    }
    __builtin_amdgcn_s_setprio(0);
  };

#define WAITV(n) asm volatile("s_waitcnt vmcnt(" #n ")" ::: "memory")
#define BAR() do { __builtin_amdgcn_s_barrier(); __builtin_amdgcn_sched_barrier(0); } while (0)
#define WAITLPC() do { if constexpr (BN == 64) WAITV(6); else WAITV(5); } while (0)

  issue(0, 0); issue(1, 1);
  WAITLPC(); BAR();
  for (int k = 0; k < 30; k += 3) {
    issue(k + 2, 2); comp(0);
    WAITLPC(); BAR();
    issue(k + 3, 0); comp(1);
    WAITLPC(); BAR();
    issue(k + 4, 1); comp(2);
    WAITLPC(); BAR();
  }
  comp(0);            // chunk 30
  WAITV(0); BAR();
  comp(1);            // chunk 31
#undef WAITV
#undef WAITLPC
#undef BAR

  // ---- epilogue: combine terms, LDS transpose, membrane update ----
  __syncthreads();
  const float thr = thresholds[c];
  float* Cl = (float*)smem;
#pragma unroll
  for (int mi = 0; mi < MI; ++mi)
#pragma unroll
    for (int nj = 0; nj < 2; ++nj)
#pragma unroll
      for (int rg = 0; rg < 4; ++rg) {
        int row = wm * (MI * 16) + mi * 16 + lh * 4 + rg;
        int col = wn * 32 + nj * 16 + lr;
        Cl[row * CLST + col] = fmaf(accm[mi][nj][rg], 0x1p-11f, acch[mi][nj][rg]);
      }
  __syncthreads();

  const int o0 = nt * BN;
  float* membp = memb + (size_t)c * PLANE_E;
  uint8_t* bufc = buf_cur + (size_t)c * PLANE_H;
  const bool last = (t == NSTEP - 1);
  constexpr int NP = (256 * BN) / (512 * 4);   // 8 (BN64) or 4 (BN32)
#pragma unroll
  for (int p = 0; p < NP; ++p) {
    int rr, c4;
    if constexpr (BN == 64) { rr = p * 32 + (tid >> 4); c4 = (tid & 15) * 4; }
    else                    { rr = p * 64 + (tid >> 3); c4 = (tid & 7) * 4; }
    int o = o0 + c4;
    float4 d = *(const float4*)&Cl[rr * CLST + c4];
    size_t idx = (size_t)rr * NN + o;
    float4 mvv = *(float4*)(membp + idx);
    mvv.x += d.x; mvv.y += d.y; mvv.z += d.z; mvv.w += d.w;
    bool g0 = thr < mvv.x, g1 = thr < mvv.y, g2 = thr < mvv.z, g3 = thr < mvv.w;
    if (g0) mvv.x -= thr;  if (g1) mvv.y -= thr;
    if (g2) mvv.z -= thr;  if (g3) mvv.w -= thr;
    *(float4*)(membp + idx) = mvv;
    // 3-bit-swizzled fp16 buf store: slot = ((o>>3)&7) ^ (rr&7)
    uint32_t ba = (uint32_t)rr * ROWB + ((uint32_t)(o >> 6) << 7)
                + ((uint32_t)(((o >> 3) & 7) ^ (rr & 7)) << 4) + ((o & 7) << 1);
    uint2 pk;
    pk.x = (g0 ? 0x3C00u : 0u) | ((g1 ? 0x3C00u : 0u) << 16);
    pk.y = (g2 ? 0x3C00u : 0u) | ((g3 ? 0x3C00u : 0u) << 16);
    *(uint2*)(bufc + ba) = pk;
    if (c == NCORE - 1) {
      float4 cv = *(float4*)(out + idx);
      cv.x += g0 ? 1.f : 0.f; cv.y += g1 ? 1.f : 0.f;
      cv.z += g2 ? 1.f : 0.f; cv.w += g3 ? 1.f : 0.f;
      if (last) { cv.x *= 0.03125f; cv.y *= 0.03125f; cv.z *= 0.03125f; cv.w *= 0.03125f; }
      *(float4*)(out + idx) = cv;
    }
  }
}

extern "C" void kernel_launch(void* const* d_in, const int* in_sizes, int n_in,
                              void* d_out, int out_size, void* d_ws, size_t ws_size,
                              hipStream_t stream) {
  const float* x   = (const float*)d_in[0];
  const float* W   = (const float*)d_in[1];
  const float* thr = (const float*)d_in[2];
  float* out = (float*)d_out;
  uint8_t* ws = (uint8_t*)d_ws;

  // layout: memb f32 16.78M | strain fp16 33.55M | buf0 8.39M | buf1 8.39M | Whm 134.2M
  float*   memb   = (float*)ws;
  uint8_t* strain = ws + 16777216;
  uint8_t* buf0   = ws + 50331648;
  uint8_t* buf1   = ws + 58720256;
  uint8_t* Whm    = ws + 67108864;

  zero_f32_kernel<<<dim3(4096), 256, 0, stream>>>(memb, 1048576);
  zero_f32_kernel<<<dim3(512),  256, 0, stream>>>(out, 131072);
  spikes_h_kernel<<<dim3(256), 256, 0, stream>>>(x, strain);
  wsplit_kernel<<<dim3(64, 32, 8), 256, 0, stream>>>(W, Whm);

  for (int t = 0; t < NSTEP; ++t) {
    int c_lo = (t > TSIM - 1) ? (t - (TSIM - 1)) : 0;
    int c_hi = (t < NCORE - 1) ? t : (NCORE - 1);
    int nc = c_hi - c_lo + 1;
    uint8_t* prev = (t & 1) ? buf0 : buf1;
    uint8_t* cur  = (t & 1) ? buf1 : buf0;
    if (nc <= 4) {
      step_mfma_kernel<32><<<dim3(nc, 64), 512, 0, stream>>>(
          Whm, thr, strain, prev, cur, memb, out, t, c_lo);
    } else {
      step_mfma_kernel<64><<<dim3(nc, 32), 512, 0, stream>>>(
          Whm, thr, strain, prev, cur, memb, out, t, c_lo);
    }
  }
}

// Round 6
// 1300.062 us; speedup vs baseline: 8.0056x; 1.1729x over previous
//
#include <hip/hip_runtime.h>
#include <stdint.h>

#define BB 256
#define NN 2048
#define NCORE 8
#define TSIM 32
#define NSTEP 39
#define PLANE_E (BB*NN)        // 524288 elements
#define PLANE_I PLANE_E        // 512 KiB i8 plane
#define AROWB 2048             // bytes per i8 row

typedef int i4v __attribute__((ext_vector_type(4)));

__device__ __forceinline__ void load_lds16(const void* g, void* l) {
  __builtin_amdgcn_global_load_lds((const __attribute__((address_space(1))) void*)g,
                                   (__attribute__((address_space(3))) void*)l, 16, 0, 0);
}

// ---------------- zero init ----------------
__global__ void zero_f32_kernel(float* __restrict__ p, int n4) {
  int i = blockIdx.x * 256 + threadIdx.x;
  if (i < n4) ((float4*)p)[i] = make_float4(0.f, 0.f, 0.f, 0.f);
}

// ---------------- spike trains, i8 {0,1}, swizzled A layout ----------------
// storage byte(b,k) = b*2048 + (k>>7)*128 + ((((k>>4)&7) ^ (b&7))<<4) + (k&15)
__global__ void spikes_kernel(const float* __restrict__ x, uint8_t* __restrict__ strain) {
  int gid = blockIdx.x * 256 + threadIdx.x;   // over BB*NN/16 = 32768
  int b = gid >> 7, kg = gid & 127;           // kg = 16-elem k-group
  const float* xp = x + (size_t)b * NN + kg * 16;
  float nsf[16], sp[16]; int ns[16];
#pragma unroll
  for (int e = 0; e < 16; ++e) {
    float nv = rintf(xp[e] * 32.0f);
    nsf[e] = nv; ns[e] = (int)nv; sp[e] = 32.0f / fmaxf(nv, 1.0f);
  }
  uint32_t dst = (uint32_t)b * 2048 + ((uint32_t)(kg >> 3) << 7)
               + ((uint32_t)((kg & 7) ^ (b & 7)) << 4);
  for (int cyc = 0; cyc < TSIM; ++cyc) {
    float ct = (float)cyc;
    uint32_t w[4] = {0u, 0u, 0u, 0u};
#pragma unroll
    for (int e = 0; e < 16; ++e) {
      bool res;
      if (ns[e] == TSIM)      res = true;
      else if (ns[e] == 0)    res = false;
      else {
        float q = floorf(ct / sp[e]);
        float m = fmodf(ct, sp[e]);
        res = (q < nsf[e]) && (floorf(m) == 0.0f);
      }
      if (res) w[e >> 2] |= 1u << ((e & 3) * 8);
    }
    uint4 pk; pk.x = w[0]; pk.y = w[1]; pk.z = w[2]; pk.w = w[3];
    *(uint4*)(strain + (size_t)cyc * PLANE_I + dst) = pk;
  }
}

// ---------------- W split: exact i8 3-plane fixed point (wi = rint(w*2^25)) ----------------
// Whm chunk id = ((c*32 + nt)*16 + kk), 24576 B; group idx = ks2*768 + p*256 + n*4 + s,
// content = plane p bytes of k = kk*128 + ks2*64 + (s ^ ((n>>1)&3))*16 + 0..15, col n.
__global__ __launch_bounds__(256) void wsplit_kernel(const float* __restrict__ W,
                                                     uint8_t* __restrict__ Whm, int c) {
  __shared__ uint32_t lds[3 * 2048];   // [p][kq(32)][n(64)] u32 (4 k-bytes each)
  int kk = blockIdx.x, nt = blockIdx.y;
  int tid = threadIdx.x, lane = tid & 63, wid = tid >> 6;
  const float* src = W + ((size_t)c * NN + (size_t)kk * 128) * NN + nt * 64 + lane;
#pragma unroll
  for (int kp = 0; kp < 8; ++kp) {
    uint32_t pk0 = 0, pk1 = 0, pk2 = 0;
#pragma unroll
    for (int q = 0; q < 4; ++q) {
      int kl = kp * 16 + wid * 4 + q;
      float w = src[(size_t)kl * NN];
      int wi = (int)rintf(w * 0x1p25f);            // exact: |wi| < 2^22
      int l8 = (int)(int8_t)(uint8_t)(wi & 0xFF);
      int r1 = (wi - l8) >> 8;
      int m8 = (int)(int8_t)(uint8_t)(r1 & 0xFF);
      int h8 = (r1 - m8) >> 8;                     // |h8| <= 64
      pk0 |= ((uint32_t)(uint8_t)h8) << (q * 8);
      pk1 |= ((uint32_t)(uint8_t)m8) << (q * 8);
      pk2 |= ((uint32_t)(uint8_t)l8) << (q * 8);
    }
    int kq = kp * 4 + wid;
    lds[0 * 2048 + kq * 64 + lane] = pk0;
    lds[1 * 2048 + kq * 64 + lane] = pk1;
    lds[2 * 2048 + kq * 64 + lane] = pk2;
  }
  __syncthreads();
  size_t chunkbase = (((size_t)c * 32 + nt) * 16 + kk) * 24576;
#pragma unroll
  for (int g = 0; g < 6; ++g) {
    int idx = g * 256 + tid;
    int ks2 = (idx >= 768) ? 1 : 0;
    int rem = idx - ks2 * 768;
    int p = rem >> 8;
    int n = (rem >> 2) & 63;
    int s = rem & 3;
    int k16 = s ^ ((n >> 1) & 3);
    int kqb = ks2 * 16 + k16 * 4;
    uint4 v;
    v.x = lds[p * 2048 + (kqb + 0) * 64 + n];
    v.y = lds[p * 2048 + (kqb + 1) * 64 + n];
    v.z = lds[p * 2048 + (kqb + 2) * 64 + n];
    v.w = lds[p * 2048 + (kqb + 3) * 64 + n];
    *(uint4*)(Whm + chunkbase + (size_t)idx * 16) = v;
  }
}

// ---------------- one pipeline step: 8 waves, BK=128, depth-2 counted pipeline ----------------
// grid (active cores, 2048/BN n-tiles), 512 threads.
template<int BN>
__global__ __launch_bounds__(512) void step_kernel(
    const uint8_t* __restrict__ Whm, const float* __restrict__ thresholds,
    const uint8_t* __restrict__ strain,
    const uint8_t* __restrict__ buf_prev, uint8_t* __restrict__ buf_cur,
    float* __restrict__ memb, float* __restrict__ out, int t, int c_lo) {
  constexpr int BCH = (BN == 64) ? 24576 : 12288;  // B bytes per BK=128 chunk
  constexpr int MI  = (BN == 64) ? 4 : 2;          // 16-row frags per wave
  constexpr int KS2 = (BN == 64) ? 12288 : 6144;   // ks2 stride in LDS B
  constexpr int PS  = (BN == 64) ? 4096 : 2048;    // plane stride in LDS B
  constexpr int CLST = BN + 4;
  __shared__ uint8_t smem[2 * 32768 + 2 * BCH];

  const int tid = threadIdx.x;
  const int c  = c_lo + blockIdx.x;
  const int nt = blockIdx.y;
  const int l = tid & 63, wid = tid >> 6;
  const int wm = (BN == 64) ? (wid >> 1) : wid;
  const int wn = (BN == 64) ? (wid & 1) : 0;
  const int lr = l & 15, lh = l >> 4;
  uint8_t* As = smem;
  uint8_t* Bs = smem + 2 * 32768;

  const uint8_t* Asrc = (c == 0) ? (strain + (size_t)t * PLANE_I)
                                 : (buf_prev + (size_t)(c - 1) * PLANE_I);
  const uint8_t* ab[4];
#pragma unroll
  for (int j = 0; j < 4; ++j) {
    int i = j * 512 + tid;
    ab[j] = Asrc + (size_t)(i >> 3) * AROWB + (i & 7) * 16;
  }
  const size_t wcb = (((size_t)c * 32 + ((BN == 64) ? nt : (nt >> 1))) * 16) * 24576;
  const uint8_t* bb[3];
  if constexpr (BN == 64) {
#pragma unroll
    for (int j = 0; j < 3; ++j) bb[j] = Whm + wcb + (size_t)(j * 512 + tid) * 16;
  } else {
    int t2 = tid & 255;
#pragma unroll
    for (int j = 0; j < 3; ++j) {
      int li = j * 256 + t2;
      int ks2 = (li >= 384) ? 1 : 0;
      int rm = li - ks2 * 384;
      int p = rm >> 7, q = rm & 127;
      bb[j] = Whm + wcb + (size_t)(ks2 * 768 + p * 256 + (nt & 1) * 128 + q) * 16;
    }
  }

  // fragment LDS byte offsets (A rows 128 B, 3-bit slot swizzle; ks toggles bit 6)
  const uint32_t base_aoff = (uint32_t)(wm * (MI * 16) + lr) * 128
                           + ((uint32_t)(lh ^ (lr & 7)) << 4);
  uint32_t bo[2];
#pragma unroll
  for (int nj = 0; nj < 2; ++nj) {
    int n = wn * 32 + nj * 16 + lr;
    bo[nj] = (uint32_t)n * 64 + ((uint32_t)(lh ^ ((n >> 1) & 3)) << 4);
  }

  i4v acc[3][MI][2];
  const i4v izero = {0, 0, 0, 0};
#pragma unroll
  for (int p = 0; p < 3; ++p)
#pragma unroll
    for (int mi = 0; mi < MI; ++mi) { acc[p][mi][0] = izero; acc[p][mi][1] = izero; }

  auto issue = [&](int kk, int slot) {
    uint8_t* Ad = As + slot * 32768;
    uint8_t* Bd = Bs + slot * BCH;
#pragma unroll
    for (int j = 0; j < 4; ++j)
      load_lds16(ab[j] + kk * 128, Ad + (j * 512 + tid) * 16);
    if constexpr (BN == 64) {
#pragma unroll
      for (int j = 0; j < 3; ++j)
        load_lds16(bb[j] + (size_t)kk * 24576, Bd + (j * 512 + tid) * 16);
    } else {
      if (tid < 256) {
#pragma unroll
        for (int j = 0; j < 3; ++j)
          load_lds16(bb[j] + (size_t)kk * 24576, Bd + (j * 256 + (tid & 255)) * 16);
      }
    }
  };

  auto comp = [&](int slot) {
    const uint8_t* Ab = As + slot * 32768;
    const uint8_t* Bb = Bs + slot * BCH;
    __builtin_amdgcn_s_setprio(1);
#pragma unroll
    for (int ks = 0; ks < 2; ++ks) {
      i4v b00 = *(const i4v*)(Bb + ks * KS2 + 0 * PS + bo[0]);
      i4v b10 = *(const i4v*)(Bb + ks * KS2 + 1 * PS + bo[0]);
      i4v b20 = *(const i4v*)(Bb + ks * KS2 + 2 * PS + bo[0]);
      i4v b01 = *(const i4v*)(Bb + ks * KS2 + 0 * PS + bo[1]);
      i4v b11 = *(const i4v*)(Bb + ks * KS2 + 1 * PS + bo[1]);
      i4v b21 = *(const i4v*)(Bb + ks * KS2 + 2 * PS + bo[1]);
#pragma unroll
      for (int mi = 0; mi < MI; ++mi) {
        i4v a = *(const i4v*)(Ab + (base_aoff ^ (ks << 6)) + mi * 2048);
        acc[0][mi][0] = __builtin_amdgcn_mfma_i32_16x16x64_i8(a, b00, acc[0][mi][0], 0, 0, 0);
        acc[1][mi][0] = __builtin_amdgcn_mfma_i32_16x16x64_i8(a, b10, acc[1][mi][0], 0, 0, 0);
        acc[2][mi][0] = __builtin_amdgcn_mfma_i32_16x16x64_i8(a, b20, acc[2][mi][0], 0, 0, 0);
        acc[0][mi][1] = __builtin_amdgcn_mfma_i32_16x16x64_i8(a, b01, acc[0][mi][1], 0, 0, 0);
        acc[1][mi][1] = __builtin_amdgcn_mfma_i32_16x16x64_i8(a, b11, acc[1][mi][1], 0, 0, 0);
        acc[2][mi][1] = __builtin_amdgcn_mfma_i32_16x16x64_i8(a, b21, acc[2][mi][1], 0, 0, 0);
      }
    }
    __builtin_amdgcn_s_setprio(0);
  };

#define WAITV(n) asm volatile("s_waitcnt vmcnt(" #n ")" ::: "memory")
#define WAITL() asm volatile("s_waitcnt lgkmcnt(0)" ::: "memory")
#define BAR() do { __builtin_amdgcn_s_barrier(); __builtin_amdgcn_sched_barrier(0); } while (0)

  issue(0, 0);
  for (int k = 0; k < 16; ++k) {
    if (k < 15) {
      issue(k + 1, (k + 1) & 1);
      if constexpr (BN == 64) { WAITV(7); }
      else { if (wid < 4) { WAITV(7); } else { WAITV(4); } }
    } else {
      WAITV(0);
    }
    BAR();                     // chunk k landed for all waves
    comp(k & 1);
    WAITL();                   // this wave's ds_reads of slot k&1 complete
    BAR();                     // slot k&1 free to overwrite next iter
  }
#undef WAITV
#undef WAITL
#undef BAR

  // ---- epilogue: exact i32 recombine -> float, LDS transpose, membrane update ----
  __syncthreads();
  const float thr = thresholds[c];
  float* Cl = (float*)smem;
#pragma unroll
  for (int mi = 0; mi < MI; ++mi)
#pragma unroll
    for (int nj = 0; nj < 2; ++nj)
#pragma unroll
      for (int rg = 0; rg < 4; ++rg) {
        int row = wm * (MI * 16) + mi * 16 + lh * 4 + rg;
        int col = wn * 32 + nj * 16 + lr;
        int di = (acc[0][mi][nj][rg] << 16) + (acc[1][mi][nj][rg] << 8) + acc[2][mi][nj][rg];
        Cl[row * CLST + col] = (float)di * 0x1p-25f;   // single RNE rounding of exact sum
      }
  __syncthreads();

  const int o0 = nt * BN;
  float* membp = memb + (size_t)c * PLANE_E;
  uint8_t* bufc = buf_cur + (size_t)c * PLANE_I;
  const bool last = (t == NSTEP - 1);
  constexpr int NP = (BN == 64) ? 8 : 4;
#pragma unroll
  for (int p = 0; p < NP; ++p) {
    int rr, c4;
    if constexpr (BN == 64) { rr = p * 32 + (tid >> 4); c4 = (tid & 15) * 4; }
    else                    { rr = p * 64 + (tid >> 3); c4 = (tid & 7) * 4; }
    int o = o0 + c4;
    float4 d = *(const float4*)&Cl[rr * CLST + c4];
    size_t idx = (size_t)rr * NN + o;
    float4 mvv = *(float4*)(membp + idx);
    mvv.x += d.x; mvv.y += d.y; mvv.z += d.z; mvv.w += d.w;
    bool g0 = thr < mvv.x, g1 = thr < mvv.y, g2 = thr < mvv.z, g3 = thr < mvv.w;
    if (g0) mvv.x -= thr;  if (g1) mvv.y -= thr;
    if (g2) mvv.z -= thr;  if (g3) mvv.w -= thr;
    *(float4*)(membp + idx) = mvv;
    // i8 swizzled buf store: byte(b,k) = b*2048 + (k>>7)*128 + ((((k>>4)&7)^(b&7))<<4) + (k&15)
    uint32_t ba = (uint32_t)rr * AROWB + ((uint32_t)(o >> 7) << 7)
                + ((uint32_t)(((o >> 4) & 7) ^ (rr & 7)) << 4) + (o & 15);
    uchar4 pk;
    pk.x = g0 ? 1 : 0; pk.y = g1 ? 1 : 0; pk.z = g2 ? 1 : 0; pk.w = g3 ? 1 : 0;
    *(uchar4*)(bufc + ba) = pk;
    if (c == NCORE - 1) {
      float4 cv = *(float4*)(out + idx);
      cv.x += g0 ? 1.f : 0.f; cv.y += g1 ? 1.f : 0.f;
      cv.z += g2 ? 1.f : 0.f; cv.w += g3 ? 1.f : 0.f;
      if (last) { cv.x *= 0.03125f; cv.y *= 0.03125f; cv.z *= 0.03125f; cv.w *= 0.03125f; }
      *(float4*)(out + idx) = cv;
    }
  }
}

extern "C" void kernel_launch(void* const* d_in, const int* in_sizes, int n_in,
                              void* d_out, int out_size, void* d_ws, size_t ws_size,
                              hipStream_t stream) {
  const float* x   = (const float*)d_in[0];
  const float* W   = (const float*)d_in[1];
  const float* thr = (const float*)d_in[2];
  float* out = (float*)d_out;
  uint8_t* ws = (uint8_t*)d_ws;

  // layout: memb f32 16.78M | strain i8 16.78M | buf0 4.19M | buf1 4.19M | Whm 100.7M
  float*   memb   = (float*)ws;
  uint8_t* strain = ws + 16777216;
  uint8_t* buf0   = ws + 33554432;
  uint8_t* buf1   = ws + 37748736;
  uint8_t* Whm    = ws + 41943040;

  zero_f32_kernel<<<dim3(4096), 256, 0, stream>>>(memb, 1048576);
  zero_f32_kernel<<<dim3(512),  256, 0, stream>>>(out, 131072);
  spikes_kernel<<<dim3(128), 256, 0, stream>>>(x, strain);
  for (int c = 0; c < NCORE; ++c)          // 8 slices: keeps each dispatch < step time
    wsplit_kernel<<<dim3(16, 32), 256, 0, stream>>>(W, Whm, c);

  for (int t = 0; t < NSTEP; ++t) {
    int c_lo = (t > TSIM - 1) ? (t - (TSIM - 1)) : 0;
    int c_hi = (t < NCORE - 1) ? t : (NCORE - 1);
    int nc = c_hi - c_lo + 1;
    uint8_t* prev = (t & 1) ? buf0 : buf1;
    uint8_t* cur  = (t & 1) ? buf1 : buf0;
    if (nc <= 4) {
      step_kernel<32><<<dim3(nc, 64), 512, 0, stream>>>(
          Whm, thr, strain, prev, cur, memb, out, t, c_lo);
    } else {
      step_kernel<64><<<dim3(nc, 32), 512, 0, stream>>>(
          Whm, thr, strain, prev, cur, memb, out, t, c_lo);
    }
  }
}